// Round 12
// baseline (309.492 us; speedup 1.0000x reference)
//
#include <hip/hip_runtime.h>
#include <hip/hip_fp16.h>

// GIN 2-layer + BN + softmax pipeline for MI355X. All tensors fp32; edges int32.
// R23: DEGREE-SORTED gather scheduling. A wave's 4 independent 16-lane groups
// run lockstep for max(4 node degrees) ~= 1.45x mean (Poisson-16) -> ~30%+
// masked-lane waste, invisible to byte counters (all bytes/ILP levers were
// null). perm[] = nodes counting-sorted by (degree bin, class): scan_a builds
// the histogram (LDS-aggregated), dbin_scan (1 blk) bases it, scan_c scatters
// ranks. Gathers process perm[slot] -> equal degrees within each wave.
// KEEP: R22 structure (293us), M=128 mlp, XCD-classed stats atomics, f16
// pipeline, BN folded in consumers, hist in prep_all.
//
// Workspace timeline (B0/B1/B2 = 25.6 MB fp32 regions; h* = f16 aliases):
//   prep_all: hist->deg ; xh=(u16*)B2 <- x ; wt* <- W*
//   gather1:  reads xh(B2)    -> h0h=(u16*)B0  (slots via perm)
//   mlp1:     A=h0h(B0)       -> hh=(u16*)B0 IN-PLACE + stats1 (8-class)
//   gather2:  reads hh(B0)+BN1(from sums) -> h2h=(u16*)B2
//   mlp2:     A=h2h(B2)       -> B1h f16 + stats2 (8-class)
//   out_proj: reads B1h (+BN2 from sums fused)

#define NNODES 50000
#define NEDGES 800000
#define HD 128
#define KOUT 64
#define NCLS 8
#define CLSW 6250            // nodes per class window (NNODES/NCLS)
#define HIST_BLKS 512        // 64 edge-chunks x 8 classes

typedef __attribute__((ext_vector_type(8))) _Float16 f16x8;
typedef __attribute__((ext_vector_type(4))) float f32x4;

__device__ __forceinline__ unsigned short f2h_bits(float f) {   // RNE f32->f16
    _Float16 h = (_Float16)f;
    return __builtin_bit_cast(unsigned short, h);
}
__device__ __forceinline__ f16x8 h8_relu(f16x8 v) {
    #pragma unroll
    for (int i = 0; i < 8; ++i) v[i] = (v[i] > (_Float16)0.f) ? v[i] : (_Float16)0.f;
    return v;
}
// BN scale/shift from 8-class sums (one channel)
__device__ __forceinline__ void bn_fold_ch(
    const float* __restrict__ ssum, const float* __restrict__ ssq,
    const float* __restrict__ gamma, const float* __restrict__ beta,
    int c, float* sc_out, float* sh_out)
{
    float s = 0.f, q = 0.f;
    #pragma unroll
    for (int g = 0; g < 8; ++g) {
        s += ssum[g * 128 + c];
        q += ssq[g * 128 + c];
    }
    const float invN = 1.0f / (float)NNODES;
    float m = s * invN;
    float var = fmaf(-m, m, q * invN);
    float rs = rsqrtf(var + 1e-5f);
    float sc = gamma[c] * rs;
    *sc_out = sc;
    *sh_out = fmaf(-m, sc, beta[c]);
}

// ===== prep: classed deg histogram (bid<512) | x -> f16 | weight transposes =====
__global__ __launch_bounds__(256) void prep_all(
    const float* __restrict__ x, unsigned short* __restrict__ xh,
    const float* __restrict__ W1a, const float* __restrict__ W1b,
    const float* __restrict__ W2a, const float* __restrict__ W2b,
    unsigned short* __restrict__ wt1a, unsigned short* __restrict__ wt1b,
    unsigned short* __restrict__ wt2a, unsigned short* __restrict__ wt2b,
    const int* __restrict__ ei, int* __restrict__ deg)
{
    __shared__ int h[CLSW];                 // 25000 B (hist blocks only)
    int bid = blockIdx.x;
    if (bid < HIST_BLKS) {                  // classed LDS histogram
        const int cls = bid & 7;
        const int lo = cls * CLSW;
        const int e0 = (bid >> 3) * 12500;  // 64 chunks x 12500 = NEDGES
        for (int i = threadIdx.x; i < CLSW; i += 256) h[i] = 0;
        __syncthreads();
        for (int e = e0 + threadIdx.x; e < e0 + 12500; e += 256) {
            unsigned d = (unsigned)(ei[NEDGES + e] - lo);
            if (d < (unsigned)CLSW) atomicAdd(&h[d], 1);
        }
        __syncthreads();
        for (int i = threadIdx.x; i < CLSW; i += 256) {
            int v = h[i];
            if (v) atomicAdd(&deg[lo + i], v);  // coalesced, XCD-local
        }
    } else if (bid < HIST_BLKS + 6250) {    // x -> f16 (float4 per thread)
        int i = (bid - HIST_BLKS) * 256 + threadIdx.x;
        float4 v = ((const float4*)x)[i];
        ushort4 o;
        o.x = f2h_bits(v.x); o.y = f2h_bits(v.y);
        o.z = f2h_bits(v.z); o.w = f2h_bits(v.w);
        ((ushort4*)xh)[i] = o;
    } else {                                // Wt[n][k] = f16(W[k][n])
        int wb = bid - (HIST_BLKS + 6250);  // 0..255
        int w = wb >> 6;
        int idx = (wb & 63) * 256 + threadIdx.x;   // 0..16383
        int n = idx >> 7, k = idx & 127;
        const float* W = (w == 0) ? W1a : (w == 1) ? W1b : (w == 2) ? W2a : W2b;
        unsigned short* Wt = (w == 0) ? wt1a : (w == 1) ? wt1b : (w == 2) ? wt2a : wt2b;
        Wt[idx] = f2h_bits(W[k * HD + n]);
    }
}

// ===== CSR scan + degree-bin histogram (key = (min(deg,63)<<3)|class) =====
__global__ __launch_bounds__(256) void scan_a(
    const int* __restrict__ deg, int* __restrict__ incl, int* __restrict__ bsum,
    int* __restrict__ dbin)
{
    __shared__ int s[256];
    __shared__ int hbin[512];
    int t = threadIdx.x, idx = blockIdx.x * 256 + t;
    hbin[t] = 0; hbin[t + 256] = 0;
    int v = (idx < NNODES) ? deg[idx] : 0;
    s[t] = v; __syncthreads();
    if (idx < NNODES) {
        int key = ((v < 63 ? v : 63) << 3) | (idx / CLSW);
        atomicAdd(&hbin[key], 1);
    }
    #pragma unroll
    for (int off = 1; off < 256; off <<= 1) {
        int tmp = (t >= off) ? s[t - off] : 0;
        __syncthreads();
        s[t] += tmp;
        __syncthreads();
    }
    if (idx < NNODES) incl[idx] = s[t];
    if (t == 255) bsum[blockIdx.x] = s[255];
    __syncthreads();
    int c0 = hbin[t];       if (c0) atomicAdd(&dbin[t], c0);
    int c1 = hbin[t + 256]; if (c1) atomicAdd(&dbin[t + 256], c1);
}

// exclusive scan of the 512 degree-bin counts
__global__ __launch_bounds__(512) void dbin_scan(
    const int* __restrict__ dbin, int* __restrict__ dbase)
{
    __shared__ int s[512];
    int t = threadIdx.x;
    int v = dbin[t];
    s[t] = v; __syncthreads();
    #pragma unroll
    for (int off = 1; off < 512; off <<= 1) {
        int tmp = (t >= off) ? s[t - off] : 0;
        __syncthreads();
        s[t] += tmp;
        __syncthreads();
    }
    dbase[t] = s[t] - v;
}

// scan_c: row_start/cur (scan_b folded) + degree-sorted perm scatter
__global__ __launch_bounds__(256) void scan_c(
    const int* __restrict__ deg, const int* __restrict__ incl,
    const int* __restrict__ bsum, const int* __restrict__ dbase,
    int* __restrict__ dcur,
    int* __restrict__ row_start, int* __restrict__ cur, int* __restrict__ perm)
{
    __shared__ int s[256];
    __shared__ int lcount[512];
    __shared__ int lbase[512];
    int b = blockIdx.x, t = threadIdx.x;
    lcount[t] = 0; lcount[t + 256] = 0;
    int p = 0;
    for (int i = t; i < b; i += 256) p += bsum[i];
    s[t] = p; __syncthreads();
    #pragma unroll
    for (int off = 128; off > 0; off >>= 1) {
        if (t < off) s[t] += s[t + off];
        __syncthreads();
    }
    int off0 = s[0];
    int idx = b * 256 + t;
    bool ok = idx < NNODES;
    int key = 0, r = 0;
    if (ok) {
        int dv = deg[idx];
        int ex = incl[idx] - dv + off0;
        row_start[idx] = ex;
        cur[idx] = ex;
        key = ((dv < 63 ? dv : 63) << 3) | (idx / CLSW);
        r = atomicAdd(&lcount[key], 1);
    }
    __syncthreads();
    int c0 = lcount[t];
    lbase[t] = c0 ? atomicAdd(&dcur[t], c0) : 0;
    int c1 = lcount[t + 256];
    lbase[t + 256] = c1 ? atomicAdd(&dcur[t + 256], c1) : 0;
    __syncthreads();
    if (ok) perm[dbase[key] + lbase[key] + r] = idx;
}

// XCD-partitioned fill: 256 chunks x 8 classes; class = blockIdx&7 owns one
// 400KB col window -> single-L2 write accumulation.
__global__ __launch_bounds__(256) void edge_fill(
    const int* __restrict__ ei, int* __restrict__ cur, int* __restrict__ col)
{
    const int cls = blockIdx.x & 7;
    const int e0 = (blockIdx.x >> 3) * 3125;
    for (int e = e0 + threadIdx.x; e < e0 + 3125; e += 256) {
        int dst = ei[NEDGES + e];
        if (dst / CLSW == cls) {
            int pos = atomicAdd(&cur[dst], 1);
            col[pos] = ei[e];
        }
    }
}

// ========== gather (f16 in/out), 16 lanes/node x 16B loads, pk-f16 math ==========
// 2 serial nodes/group (32 nodes/block, grid 1563 = full TLP) + 8-deep load
// unroll. Nodes taken from degree-sorted perm -> equal degrees within a wave.
// BN=true: scale/shift computed in prologue from 8-class sums.
template<bool BN>
__global__ __launch_bounds__(256) void gin_gather_w(
    const unsigned short* __restrict__ Xh, const int* __restrict__ col,
    const int* __restrict__ rs, const int* __restrict__ re,
    const int* __restrict__ perm,
    const float* __restrict__ eps,
    const float* __restrict__ ssum, const float* __restrict__ ssq,
    const float* __restrict__ gamma, const float* __restrict__ beta,
    unsigned short* __restrict__ H0h)
{
    __shared__ float s_sc[128], s_sh[128];
    const int t = threadIdx.x;
    const int g = t >> 4;            // 16 groups
    const int lane = t & 15;         // 16B per lane -> 8 feats
    const f16x8* X8 = (const f16x8*)Xh;        // 16 f16x8 per row
    const float alphaf = 1.f + eps[0];

    if (BN) {
        if (t < 128) bn_fold_ch(ssum, ssq, gamma, beta, t, &s_sc[t], &s_sh[t]);
        __syncthreads();
    }

    f16x8 sc8, sh8, al8;
    #pragma unroll
    for (int i = 0; i < 8; ++i) al8[i] = (_Float16)alphaf;
    if (BN) {
        #pragma unroll
        for (int i = 0; i < 8; ++i) {
            sc8[i] = (_Float16)s_sc[lane * 8 + i];
            sh8[i] = (_Float16)s_sh[lane * 8 + i];
        }
    }

    #pragma unroll 1
    for (int nn = 0; nn < 2; ++nn) {
        int slot = blockIdx.x * 32 + nn * 16 + g;
        if (slot >= NNODES) continue;
        int node = perm[slot];

        f16x8 acc = X8[(long)node * 16 + lane];
        if (BN) acc = h8_relu(acc * sc8 + sh8);
        acc = acc * al8;

        int j = rs[node], end = re[node];
        for (; j + 7 < end; j += 8) {
            int c0 = col[j],     c1 = col[j + 1], c2 = col[j + 2], c3 = col[j + 3];
            int c4 = col[j + 4], c5 = col[j + 5], c6 = col[j + 6], c7 = col[j + 7];
            f16x8 u0 = X8[(long)c0 * 16 + lane];
            f16x8 u1 = X8[(long)c1 * 16 + lane];
            f16x8 u2 = X8[(long)c2 * 16 + lane];
            f16x8 u3 = X8[(long)c3 * 16 + lane];
            f16x8 u4 = X8[(long)c4 * 16 + lane];
            f16x8 u5 = X8[(long)c5 * 16 + lane];
            f16x8 u6 = X8[(long)c6 * 16 + lane];
            f16x8 u7 = X8[(long)c7 * 16 + lane];
            if (BN) {
                u0 = h8_relu(u0 * sc8 + sh8); u1 = h8_relu(u1 * sc8 + sh8);
                u2 = h8_relu(u2 * sc8 + sh8); u3 = h8_relu(u3 * sc8 + sh8);
                u4 = h8_relu(u4 * sc8 + sh8); u5 = h8_relu(u5 * sc8 + sh8);
                u6 = h8_relu(u6 * sc8 + sh8); u7 = h8_relu(u7 * sc8 + sh8);
            }
            acc += ((u0 + u1) + (u2 + u3)) + ((u4 + u5) + (u6 + u7));
        }
        for (; j + 3 < end; j += 4) {
            f16x8 u0 = X8[(long)col[j]     * 16 + lane];
            f16x8 u1 = X8[(long)col[j + 1] * 16 + lane];
            f16x8 u2 = X8[(long)col[j + 2] * 16 + lane];
            f16x8 u3 = X8[(long)col[j + 3] * 16 + lane];
            if (BN) {
                u0 = h8_relu(u0 * sc8 + sh8); u1 = h8_relu(u1 * sc8 + sh8);
                u2 = h8_relu(u2 * sc8 + sh8); u3 = h8_relu(u3 * sc8 + sh8);
            }
            acc += (u0 + u1) + (u2 + u3);
        }
        for (; j < end; ++j) {
            f16x8 u = X8[(long)col[j] * 16 + lane];
            if (BN) u = h8_relu(u * sc8 + sh8);
            acc += u;
        }

        ((f16x8*)H0h)[(long)node * 16 + lane] = acc;
    }
}

// ========== fused MLP: C = (ReLU(A@Wa + ba))@Wb + bb, + per-col stats ==========
// M=128 tile, 512 threads (8 waves). LDS: Wsa(34816)+Wsb(34816)=69632 B.
// Cs16 f16 overlays Wsa after GEMM1; CsF fp32 overlays whole region after
// GEMM2; redp overlays base after CsF reads. Output f16 (Cb).
// Stats atomics XCD-classed: [8][128]; class = blockIdx&7.
__global__ __launch_bounds__(512) void mlp_mfma(
    const unsigned short* __restrict__ A,      // [M][128] f16
    const unsigned short* __restrict__ Wta,    // [128][128] f16 N-major
    const float* __restrict__ biasa,
    const unsigned short* __restrict__ Wtb,
    const float* __restrict__ biasb,
    unsigned short* __restrict__ Cb,           // f16 out
    float* __restrict__ out_sum, float* __restrict__ out_sq)
{
    __shared__ float4 smem4[69632 / 16];
    char* smem = (char*)smem4;
    _Float16 (*Wsa)[136]  = (_Float16(*)[136])smem;            // 128x136 f16
    _Float16 (*Wsb)[136]  = (_Float16(*)[136])(smem + 34816);  // 128x136 f16
    _Float16 (*Cs16)[136] = (_Float16(*)[136])smem;            // overlays Wsa
    float (*CsF)[132]     = (float(*)[132])smem;               // 128x132 f32 = 67584
    float* redp           = (float*)smem;                      // 2*16*128 f32 = 16KB

    const int t = threadIdx.x;
    const int wave = t >> 6, lane = t & 63;
    const int m16 = lane & 15, quad = lane >> 4;
    const int row0 = blockIdx.x * 128;
    const int arow = row0 + wave * 16 + m16;

    #pragma unroll
    for (int i = 0; i < 4; ++i) {
        int idx = t + i * 512;
        int r = idx >> 4, s = idx & 15;
        *(float4*)&Wsa[r][s * 8] = ((const float4*)Wta)[idx];
        *(float4*)&Wsb[r][s * 8] = ((const float4*)Wtb)[idx];
    }

    f16x8 afrag[4];
    if (arow < NNODES) {
        const _Float16* ar = (const _Float16*)A + (long)arow * HD + quad * 8;
        #pragma unroll
        for (int kc = 0; kc < 4; ++kc)
            afrag[kc] = *(const f16x8*)(ar + kc * 32);
    } else {
        #pragma unroll
        for (int kc = 0; kc < 4; ++kc)
            afrag[kc] = f16x8{0, 0, 0, 0, 0, 0, 0, 0};
    }
    __syncthreads();

    // ---- GEMM 1 (reads Wsa)
    f32x4 accs[8];
    #pragma unroll
    for (int np = 0; np < 8; np += 2) {
        f32x4 a0 = {0.f, 0.f, 0.f, 0.f};
        f32x4 a1 = {0.f, 0.f, 0.f, 0.f};
        const _Float16* b0 = &Wsa[np * 16 + m16][quad * 8];
        const _Float16* b1 = &Wsa[(np + 1) * 16 + m16][quad * 8];
        #pragma unroll
        for (int kc = 0; kc < 4; ++kc) {
            f16x8 f0 = *(const f16x8*)(b0 + kc * 32);
            f16x8 f1 = *(const f16x8*)(b1 + kc * 32);
            a0 = __builtin_amdgcn_mfma_f32_16x16x32_f16(afrag[kc], f0, a0, 0, 0, 0);
            a1 = __builtin_amdgcn_mfma_f32_16x16x32_f16(afrag[kc], f1, a1, 0, 0, 0);
        }
        accs[np] = a0; accs[np + 1] = a1;
    }
    __syncthreads();                       // all Wsa reads done

    // bias+ReLU -> f16 into Cs16 (overlays Wsa); rows disjoint per wave
    #pragma unroll
    for (int np = 0; np < 8; ++np) {
        int c = np * 16 + m16;
        float bb = biasa[c];
        #pragma unroll
        for (int r = 0; r < 4; ++r)
            Cs16[wave * 16 + quad * 4 + r][c] =
                (_Float16)fmaxf(accs[np][r] + bb, 0.f);
    }
    __syncthreads();                       // Cs16 complete

    // ---- GEMM 2 (A2 from Cs16, weights Wsb)
    f16x8 afrag2[4];
    {
        const int crow = wave * 16 + m16;
        #pragma unroll
        for (int kc = 0; kc < 4; ++kc)
            afrag2[kc] = *(const f16x8*)&Cs16[crow][quad * 8 + kc * 32];
    }
    #pragma unroll
    for (int np = 0; np < 8; np += 2) {
        f32x4 a0 = {0.f, 0.f, 0.f, 0.f};
        f32x4 a1 = {0.f, 0.f, 0.f, 0.f};
        const _Float16* b0 = &Wsb[np * 16 + m16][quad * 8];
        const _Float16* b1 = &Wsb[(np + 1) * 16 + m16][quad * 8];
        #pragma unroll
        for (int kc = 0; kc < 4; ++kc) {
            f16x8 f0 = *(const f16x8*)(b0 + kc * 32);
            f16x8 f1 = *(const f16x8*)(b1 + kc * 32);
            a0 = __builtin_amdgcn_mfma_f32_16x16x32_f16(afrag2[kc], f0, a0, 0, 0, 0);
            a1 = __builtin_amdgcn_mfma_f32_16x16x32_f16(afrag2[kc], f1, a1, 0, 0, 0);
        }
        accs[np] = a0; accs[np + 1] = a1;
    }
    __syncthreads();                       // all Cs16/Wsb reads done

    // epilogue fp32 C over whole region
    #pragma unroll
    for (int np = 0; np < 8; ++np) {
        int c = np * 16 + m16;
        float bb = biasb[c];
        #pragma unroll
        for (int r = 0; r < 4; ++r)
            CsF[wave * 16 + quad * 4 + r][c] = accs[np][r] + bb;
    }
    __syncthreads();                       // CsF complete

    const int s4 = t & 31;                 // float4 col
    const int rb = t >> 5;                 // 16 row groups
    float lsum[4] = {}, lsq[4] = {};
    #pragma unroll
    for (int i = 0; i < 8; ++i) {
        int r = rb + i * 16;
        int row = row0 + r;
        float4 v = *(const float4*)&CsF[r][s4 * 4];
        if (row < NNODES) {
            ushort4 o;
            o.x = f2h_bits(v.x); o.y = f2h_bits(v.y);
            o.z = f2h_bits(v.z); o.w = f2h_bits(v.w);
            ((ushort4*)Cb)[(long)row * 32 + s4] = o;
            lsum[0] += v.x; lsum[1] += v.y; lsum[2] += v.z; lsum[3] += v.w;
            lsq[0] = fmaf(v.x, v.x, lsq[0]);
            lsq[1] = fmaf(v.y, v.y, lsq[1]);
            lsq[2] = fmaf(v.z, v.z, lsq[2]);
            lsq[3] = fmaf(v.w, v.w, lsq[3]);
        }
    }
    __syncthreads();                       // CsF reads done before redp overlay

    #pragma unroll
    for (int j = 0; j < 4; ++j) {
        redp[(0 * 16 + rb) * 128 + s4 * 4 + j] = lsum[j];
        redp[(1 * 16 + rb) * 128 + s4 * 4 + j] = lsq[j];
    }
    __syncthreads();
    if (t < 128) {
        float s = 0.f, q = 0.f;
        #pragma unroll
        for (int g = 0; g < 16; ++g) {
            s += redp[g * 128 + t];
            q += redp[(16 + g) * 128 + t];
        }
        const int cls = blockIdx.x & 7;            // XCD-classed stats region
        atomicAdd(&out_sum[cls * 128 + t], s);
        atomicAdd(&out_sq[cls * 128 + t],  q);
    }
}

// ========== projection + softmax; BN2 (from 8-class sums) + ReLU fused ==========
__global__ __launch_bounds__(256) void out_proj_softmax(
    const unsigned short* __restrict__ Hh, const float* __restrict__ Wout,
    const float* __restrict__ ssum, const float* __restrict__ ssq,
    const float* __restrict__ gamma, const float* __restrict__ beta,
    const float* __restrict__ log_tau,
    float* __restrict__ outS, float* __restrict__ outL)
{
    __shared__ float As[HD][20];
    __shared__ float s_sc[128], s_sh[128];
    const int t = threadIdx.x;
    const long row0 = (long)blockIdx.x * 16;

    if (t < 128) bn_fold_ch(ssum, ssq, gamma, beta, t, &s_sc[t], &s_sh[t]);
    __syncthreads();

    // 16 rows x 128 feats f16: thread t reads 8 contiguous f16 (16B)
    {
        int r = t >> 4;                    // 0..15
        int c0 = (t & 15) * 8;             // 0..120
        f16x8 v8 = *(const f16x8*)(Hh + (row0 + r) * HD + c0);
        #pragma unroll
        for (int i = 0; i < 8; ++i) {
            int cc = c0 + i;
            As[cc][r] = fmaxf(fmaf((float)v8[i], s_sc[cc], s_sh[cc]), 0.f);
        }
    }
    __syncthreads();

    const int c = t & 63;
    const int g = t >> 6;
    float acc[4] = {};

    float wq[8];
    #pragma unroll
    for (int i = 0; i < 8; ++i) wq[i] = Wout[i * KOUT + c];

    #pragma unroll 1
    for (int kc = 0; kc < HD; kc += 8) {
        float wn[8];
        if (kc + 8 < HD) {
            #pragma unroll
            for (int i = 0; i < 8; ++i) wn[i] = Wout[(kc + 8 + i) * KOUT + c];
        }
        #pragma unroll
        for (int i = 0; i < 8; ++i) {
            float4 a = *(const float4*)&As[kc + i][g * 4];
            acc[0] = fmaf(a.x, wq[i], acc[0]);
            acc[1] = fmaf(a.y, wq[i], acc[1]);
            acc[2] = fmaf(a.z, wq[i], acc[2]);
            acc[3] = fmaf(a.w, wq[i], acc[3]);
        }
        if (kc + 8 < HD) {
            #pragma unroll
            for (int i = 0; i < 8; ++i) wq[i] = wn[i];
        }
    }

    float inv_tau = __expf(-log_tau[0]);
    #pragma unroll
    for (int i = 0; i < 4; ++i) {
        float z = acc[i] * inv_tau;
        float m = z;
        #pragma unroll
        for (int o = 32; o > 0; o >>= 1) m = fmaxf(m, __shfl_xor(m, o));
        float e = __expf(z - m);
        float s = e;
        #pragma unroll
        for (int o = 32; o > 0; o >>= 1) s += __shfl_xor(s, o);
        long oi = (row0 + g * 4 + i) * KOUT + c;
        outS[oi] = e / s;
        outL[oi] = acc[i];
    }
}

extern "C" void kernel_launch(void* const* d_in, const int* in_sizes, int n_in,
                              void* d_out, int out_size, void* d_ws, size_t ws_size,
                              hipStream_t stream)
{
    const float* x      = (const float*)d_in[0];
    const int*   ei     = (const int*)d_in[1];
    const float* W1a    = (const float*)d_in[2];
    const float* b1a    = (const float*)d_in[3];
    const float* W1b    = (const float*)d_in[4];
    const float* b1b    = (const float*)d_in[5];
    const float* eps1   = (const float*)d_in[6];
    const float* gamma1 = (const float*)d_in[7];
    const float* beta1  = (const float*)d_in[8];
    const float* W2a    = (const float*)d_in[9];
    const float* b2a    = (const float*)d_in[10];
    const float* W2b    = (const float*)d_in[11];
    const float* b2b    = (const float*)d_in[12];
    const float* eps2   = (const float*)d_in[13];
    const float* gamma2 = (const float*)d_in[14];
    const float* beta2  = (const float*)d_in[15];
    const float* Wout   = (const float*)d_in[16];
    const float* ltau   = (const float*)d_in[17];

    const size_t NB = (size_t)NNODES * HD;
    float* B0 = (float*)d_ws;
    float* B1 = B0 + NB;
    float* B2 = B1 + NB;
    float* ST = B2 + NB;             // stats: 4 x [8][128] classed
    float* sum1 = ST, *sq1 = ST + 1024, *sum2 = ST + 2048, *sq2 = ST + 3072;

    unsigned short* xh  = (unsigned short*)B2;   // f16 x (CSR + gather1)
    unsigned short* h0h = (unsigned short*)B0;   // gather1 out; mlp1 in-place -> hh
    unsigned short* hh  = (unsigned short*)B0;   // h1 f16
    unsigned short* h2h = (unsigned short*)B2;   // gather2 out
    unsigned short* B1h = (unsigned short*)B1;   // h2 f16 (mlp2 out)

    int* I0        = (int*)(ST + 4096);
    int* deg       = I0;
    int* incl      = I0 + 50048;
    int* row_start = I0 + 2 * 50048;
    int* cur       = I0 + 3 * 50048;
    int* perm      = I0 + 4 * 50048;
    int* bsum      = I0 + 5 * 50048;            // 256
    int* dbin      = bsum + 256;                // 512
    int* dbase     = dbin + 512;                // 512
    int* dcur      = dbase + 512;               // 512
    int* col       = dcur + 512;                // NEDGES ints
    unsigned short* wt1a = (unsigned short*)(col + NEDGES);  // 4 x 128x128 f16
    unsigned short* wt1b = wt1a + HD * HD;
    unsigned short* wt2a = wt1b + HD * HD;
    unsigned short* wt2b = wt2a + HD * HD;

    const int SCAN_BLKS = (NNODES + 255) / 256;   // 196
    const int GEMM_BLKS = (NNODES + 127) / 128;   // 391 (M=128 tile)
    const int GATH_BLKS = (NNODES + 31) / 32;     // 1563 (32 nodes/block)

    hipMemsetAsync(ST, 0, 4096 * sizeof(float), stream);
    hipMemsetAsync(deg, 0, NNODES * sizeof(int), stream);
    hipMemsetAsync(dbin, 0, 1536 * sizeof(int), stream);   // dbin+dbase+dcur
    prep_all<<<HIST_BLKS + 6506, 256, 0, stream>>>(x, xh, W1a, W1b, W2a, W2b,
                                                   wt1a, wt1b, wt2a, wt2b, ei, deg);
    scan_a<<<SCAN_BLKS, 256, 0, stream>>>(deg, incl, bsum, dbin);
    dbin_scan<<<1, 512, 0, stream>>>(dbin, dbase);
    scan_c<<<SCAN_BLKS, 256, 0, stream>>>(deg, incl, bsum, dbase, dcur,
                                          row_start, cur, perm);
    edge_fill<<<2048, 256, 0, stream>>>(ei, cur, col);

    // ---- layer 1
    gin_gather_w<false><<<GATH_BLKS, 256, 0, stream>>>(
        xh, col, row_start, cur, perm, eps1,
        nullptr, nullptr, nullptr, nullptr, h0h);
    mlp_mfma<<<GEMM_BLKS, 512, 0, stream>>>(
        h0h, wt1a, b1a, wt1b, b1b, hh, sum1, sq1);

    // ---- layer 2 (BN1 from 8-class sums, fused into gather prologue)
    gin_gather_w<true><<<GATH_BLKS, 256, 0, stream>>>(
        hh, col, row_start, cur, perm, eps2,
        sum1, sq1, gamma1, beta1, h2h);
    mlp_mfma<<<GEMM_BLKS, 512, 0, stream>>>(
        h2h, wt2a, b2a, wt2b, b2b, B1h, sum2, sq2);

    // ---- projection + softmax (BN2 from 8-class sums + ReLU fused on load)
    out_proj_softmax<<<NNODES / 16, 256, 0, stream>>>(
        B1h, Wout, sum2, sq2, gamma2, beta2, ltau,
        (float*)d_out, (float*)d_out + (size_t)NNODES * KOUT);
}

// Round 13
// 296.868 us; speedup vs baseline: 1.0425x; 1.0425x over previous
//
#include <hip/hip_runtime.h>
#include <hip/hip_fp16.h>

// GIN 2-layer + BN + softmax pipeline for MI355X. All tensors fp32; edges int32.
// R24: REVERT to R21 (best measured: 292.7us). R23's degree-sorted perm
// regressed +16us: perm indirection + scattered node order destroyed the
// contiguous rs/re/self-row/H0h streams a block previously enjoyed; balance
// gain (if any) was swamped. Divergence theory falsified.
// Converged structure: f16 pipeline; hist folded in prep_all; scan_b folded
// into scan_c; XCD-classed edge_fill + stats atomics; 2-node/group gather
// (full TLP) w/ 8-deep unroll; M=128 512-thread mlp_mfma; bn_prep separate.
//
// Workspace timeline (B0/B1/B2 = 25.6 MB fp32 regions; h* = f16 aliases):
//   prep_all: hist->deg ; xh=(u16*)B2 <- x ; wt* <- W*
//   gather1:  reads xh(B2)    -> h0h=(u16*)B0
//   mlp1:     A=h0h(B0)       -> hh=(u16*)B0 IN-PLACE + stats1 (8-class)
//   gather2:  reads hh(B0)+BN -> h2h=(u16*)B2 (kills xh, OK)
//   mlp2:     A=h2h(B2)       -> h2 fp32 = B1 + stats2 (8-class)
//   out_proj: reads B1 (+BN2 fused)

#define NNODES 50000
#define NEDGES 800000
#define HD 128
#define KOUT 64
#define NCLS 8
#define CLSW 6250            // nodes per class window (NNODES/NCLS)
#define HIST_BLKS 512        // 64 edge-chunks x 8 classes

typedef __attribute__((ext_vector_type(8))) _Float16 f16x8;
typedef __attribute__((ext_vector_type(4))) float f32x4;

__device__ __forceinline__ unsigned short f2h_bits(float f) {   // RNE f32->f16
    _Float16 h = (_Float16)f;
    return __builtin_bit_cast(unsigned short, h);
}
__device__ __forceinline__ f16x8 h8_relu(f16x8 v) {
    #pragma unroll
    for (int i = 0; i < 8; ++i) v[i] = (v[i] > (_Float16)0.f) ? v[i] : (_Float16)0.f;
    return v;
}

// ===== prep: classed deg histogram (bid<512) | x -> f16 | weight transposes =====
__global__ __launch_bounds__(256) void prep_all(
    const float* __restrict__ x, unsigned short* __restrict__ xh,
    const float* __restrict__ W1a, const float* __restrict__ W1b,
    const float* __restrict__ W2a, const float* __restrict__ W2b,
    unsigned short* __restrict__ wt1a, unsigned short* __restrict__ wt1b,
    unsigned short* __restrict__ wt2a, unsigned short* __restrict__ wt2b,
    const int* __restrict__ ei, int* __restrict__ deg)
{
    __shared__ int h[CLSW];                 // 25000 B (hist blocks only)
    int bid = blockIdx.x;
    if (bid < HIST_BLKS) {                  // classed LDS histogram
        const int cls = bid & 7;
        const int lo = cls * CLSW;
        const int e0 = (bid >> 3) * 12500;  // 64 chunks x 12500 = NEDGES
        for (int i = threadIdx.x; i < CLSW; i += 256) h[i] = 0;
        __syncthreads();
        for (int e = e0 + threadIdx.x; e < e0 + 12500; e += 256) {
            unsigned d = (unsigned)(ei[NEDGES + e] - lo);
            if (d < (unsigned)CLSW) atomicAdd(&h[d], 1);
        }
        __syncthreads();
        for (int i = threadIdx.x; i < CLSW; i += 256) {
            int v = h[i];
            if (v) atomicAdd(&deg[lo + i], v);  // coalesced, XCD-local
        }
    } else if (bid < HIST_BLKS + 6250) {    // x -> f16 (float4 per thread)
        int i = (bid - HIST_BLKS) * 256 + threadIdx.x;
        float4 v = ((const float4*)x)[i];
        ushort4 o;
        o.x = f2h_bits(v.x); o.y = f2h_bits(v.y);
        o.z = f2h_bits(v.z); o.w = f2h_bits(v.w);
        ((ushort4*)xh)[i] = o;
    } else {                                // Wt[n][k] = f16(W[k][n])
        int wb = bid - (HIST_BLKS + 6250);  // 0..255
        int w = wb >> 6;
        int idx = (wb & 63) * 256 + threadIdx.x;   // 0..16383
        int n = idx >> 7, k = idx & 127;
        const float* W = (w == 0) ? W1a : (w == 1) ? W1b : (w == 2) ? W2a : W2b;
        unsigned short* Wt = (w == 0) ? wt1a : (w == 1) ? wt1b : (w == 2) ? wt2a : wt2b;
        Wt[idx] = f2h_bits(W[k * HD + n]);
    }
}

// ================= CSR build =================
__global__ __launch_bounds__(256) void scan_a(
    const int* __restrict__ deg, int* __restrict__ incl, int* __restrict__ bsum)
{
    __shared__ int s[256];
    int t = threadIdx.x, idx = blockIdx.x * 256 + t;
    int v = (idx < NNODES) ? deg[idx] : 0;
    s[t] = v; __syncthreads();
    #pragma unroll
    for (int off = 1; off < 256; off <<= 1) {
        int tmp = (t >= off) ? s[t - off] : 0;
        __syncthreads();
        s[t] += tmp;
        __syncthreads();
    }
    if (idx < NNODES) incl[idx] = s[t];
    if (t == 255) bsum[blockIdx.x] = s[255];
}

// scan_c with scan_b folded in: block offset = reduce(bsum[0..b-1])
__global__ __launch_bounds__(256) void scan_c(
    const int* __restrict__ deg, const int* __restrict__ incl,
    const int* __restrict__ bsum,
    int* __restrict__ row_start, int* __restrict__ cur)
{
    __shared__ int s[256];
    int b = blockIdx.x, t = threadIdx.x;
    int p = 0;
    for (int i = t; i < b; i += 256) p += bsum[i];
    s[t] = p; __syncthreads();
    #pragma unroll
    for (int off = 128; off > 0; off >>= 1) {
        if (t < off) s[t] += s[t + off];
        __syncthreads();
    }
    int off0 = s[0];
    int idx = b * 256 + t;
    if (idx >= NNODES) return;
    int ex = incl[idx] - deg[idx] + off0;
    row_start[idx] = ex;
    cur[idx] = ex;
}

// XCD-partitioned fill: 256 chunks x 8 classes; class = blockIdx&7 owns one
// 400KB col window -> single-L2 write accumulation.
__global__ __launch_bounds__(256) void edge_fill(
    const int* __restrict__ ei, int* __restrict__ cur, int* __restrict__ col)
{
    const int cls = blockIdx.x & 7;
    const int e0 = (blockIdx.x >> 3) * 3125;
    for (int e = e0 + threadIdx.x; e < e0 + 3125; e += 256) {
        int dst = ei[NEDGES + e];
        if (dst / CLSW == cls) {
            int pos = atomicAdd(&cur[dst], 1);
            col[pos] = ei[e];
        }
    }
}

// ========== gather (f16 in/out), 16 lanes/node x 16B loads, pk-f16 math ==========
// 2 serial nodes/group (32 nodes/block, grid 1563 = full TLP) + 8-deep load
// unroll (ILP for the L3-latency-bound random reads).
template<bool BN>
__global__ __launch_bounds__(256) void gin_gather_w(
    const unsigned short* __restrict__ Xh, const int* __restrict__ col,
    const int* __restrict__ rs, const int* __restrict__ re,
    const float* __restrict__ eps,
    const float* __restrict__ scale, const float* __restrict__ shift,
    unsigned short* __restrict__ H0h)
{
    const int t = threadIdx.x;
    const int g = t >> 4;            // 16 groups
    const int lane = t & 15;         // 16B per lane -> 8 feats
    const f16x8* X8 = (const f16x8*)Xh;        // 16 f16x8 per row
    const float alphaf = 1.f + eps[0];

    f16x8 sc8, sh8, al8;
    #pragma unroll
    for (int i = 0; i < 8; ++i) al8[i] = (_Float16)alphaf;
    if (BN) {
        #pragma unroll
        for (int i = 0; i < 8; ++i) {
            sc8[i] = (_Float16)scale[lane * 8 + i];
            sh8[i] = (_Float16)shift[lane * 8 + i];
        }
    }

    #pragma unroll 1
    for (int nn = 0; nn < 2; ++nn) {
        int node = blockIdx.x * 32 + nn * 16 + g;
        if (node >= NNODES) continue;

        f16x8 acc = X8[(long)node * 16 + lane];
        if (BN) acc = h8_relu(acc * sc8 + sh8);
        acc = acc * al8;

        int j = rs[node], end = re[node];
        for (; j + 7 < end; j += 8) {
            int c0 = col[j],     c1 = col[j + 1], c2 = col[j + 2], c3 = col[j + 3];
            int c4 = col[j + 4], c5 = col[j + 5], c6 = col[j + 6], c7 = col[j + 7];
            f16x8 u0 = X8[(long)c0 * 16 + lane];
            f16x8 u1 = X8[(long)c1 * 16 + lane];
            f16x8 u2 = X8[(long)c2 * 16 + lane];
            f16x8 u3 = X8[(long)c3 * 16 + lane];
            f16x8 u4 = X8[(long)c4 * 16 + lane];
            f16x8 u5 = X8[(long)c5 * 16 + lane];
            f16x8 u6 = X8[(long)c6 * 16 + lane];
            f16x8 u7 = X8[(long)c7 * 16 + lane];
            if (BN) {
                u0 = h8_relu(u0 * sc8 + sh8); u1 = h8_relu(u1 * sc8 + sh8);
                u2 = h8_relu(u2 * sc8 + sh8); u3 = h8_relu(u3 * sc8 + sh8);
                u4 = h8_relu(u4 * sc8 + sh8); u5 = h8_relu(u5 * sc8 + sh8);
                u6 = h8_relu(u6 * sc8 + sh8); u7 = h8_relu(u7 * sc8 + sh8);
            }
            acc += ((u0 + u1) + (u2 + u3)) + ((u4 + u5) + (u6 + u7));
        }
        for (; j + 3 < end; j += 4) {
            f16x8 u0 = X8[(long)col[j]     * 16 + lane];
            f16x8 u1 = X8[(long)col[j + 1] * 16 + lane];
            f16x8 u2 = X8[(long)col[j + 2] * 16 + lane];
            f16x8 u3 = X8[(long)col[j + 3] * 16 + lane];
            if (BN) {
                u0 = h8_relu(u0 * sc8 + sh8); u1 = h8_relu(u1 * sc8 + sh8);
                u2 = h8_relu(u2 * sc8 + sh8); u3 = h8_relu(u3 * sc8 + sh8);
            }
            acc += (u0 + u1) + (u2 + u3);
        }
        for (; j < end; ++j) {
            f16x8 u = X8[(long)col[j] * 16 + lane];
            if (BN) u = h8_relu(u * sc8 + sh8);
            acc += u;
        }

        ((f16x8*)H0h)[(long)node * 16 + lane] = acc;
    }
}

// ========== fused MLP: C = (ReLU(A@Wa + ba))@Wb + bb, + per-col stats ==========
// M=128 tile, 512 threads (8 waves). LDS: Wsa(34816)+Wsb(34816)=69632 B.
// Cs16 f16[128][136] overlays Wsa after GEMM1; CsF fp32[128][132] overlays the
// whole region after GEMM2; redp (16KB) overlays base after CsF reads.
// Stats atomics XCD-classed: out_sum/out_sq are [8][128]; class = blockIdx&7.
__global__ __launch_bounds__(512) void mlp_mfma(
    const unsigned short* __restrict__ A,      // [M][128] f16
    const unsigned short* __restrict__ Wta,    // [128][128] f16 N-major
    const float* __restrict__ biasa,
    const unsigned short* __restrict__ Wtb,
    const float* __restrict__ biasb,
    unsigned short* __restrict__ Cb,           // optional f16 out
    float* __restrict__ Cf,                    // optional fp32 out
    float* __restrict__ out_sum, float* __restrict__ out_sq)
{
    __shared__ float4 smem4[69632 / 16];
    char* smem = (char*)smem4;
    _Float16 (*Wsa)[136]  = (_Float16(*)[136])smem;            // 128x136 f16
    _Float16 (*Wsb)[136]  = (_Float16(*)[136])(smem + 34816);  // 128x136 f16
    _Float16 (*Cs16)[136] = (_Float16(*)[136])smem;            // overlays Wsa
    float (*CsF)[132]     = (float(*)[132])smem;               // 128x132 f32 = 67584
    float* redp           = (float*)smem;                      // 2*16*128 f32 = 16KB

    const int t = threadIdx.x;
    const int wave = t >> 6, lane = t & 63;
    const int m16 = lane & 15, quad = lane >> 4;
    const int row0 = blockIdx.x * 128;
    const int arow = row0 + wave * 16 + m16;

    #pragma unroll
    for (int i = 0; i < 4; ++i) {
        int idx = t + i * 512;
        int r = idx >> 4, s = idx & 15;
        *(float4*)&Wsa[r][s * 8] = ((const float4*)Wta)[idx];
        *(float4*)&Wsb[r][s * 8] = ((const float4*)Wtb)[idx];
    }

    f16x8 afrag[4];
    if (arow < NNODES) {
        const _Float16* ar = (const _Float16*)A + (long)arow * HD + quad * 8;
        #pragma unroll
        for (int kc = 0; kc < 4; ++kc)
            afrag[kc] = *(const f16x8*)(ar + kc * 32);
    } else {
        #pragma unroll
        for (int kc = 0; kc < 4; ++kc)
            afrag[kc] = f16x8{0, 0, 0, 0, 0, 0, 0, 0};
    }
    __syncthreads();

    // ---- GEMM 1 (reads Wsa)
    f32x4 accs[8];
    #pragma unroll
    for (int np = 0; np < 8; np += 2) {
        f32x4 a0 = {0.f, 0.f, 0.f, 0.f};
        f32x4 a1 = {0.f, 0.f, 0.f, 0.f};
        const _Float16* b0 = &Wsa[np * 16 + m16][quad * 8];
        const _Float16* b1 = &Wsa[(np + 1) * 16 + m16][quad * 8];
        #pragma unroll
        for (int kc = 0; kc < 4; ++kc) {
            f16x8 f0 = *(const f16x8*)(b0 + kc * 32);
            f16x8 f1 = *(const f16x8*)(b1 + kc * 32);
            a0 = __builtin_amdgcn_mfma_f32_16x16x32_f16(afrag[kc], f0, a0, 0, 0, 0);
            a1 = __builtin_amdgcn_mfma_f32_16x16x32_f16(afrag[kc], f1, a1, 0, 0, 0);
        }
        accs[np] = a0; accs[np + 1] = a1;
    }
    __syncthreads();                       // all Wsa reads done

    // bias+ReLU -> f16 into Cs16 (overlays Wsa); rows disjoint per wave
    #pragma unroll
    for (int np = 0; np < 8; ++np) {
        int c = np * 16 + m16;
        float bb = biasa[c];
        #pragma unroll
        for (int r = 0; r < 4; ++r)
            Cs16[wave * 16 + quad * 4 + r][c] =
                (_Float16)fmaxf(accs[np][r] + bb, 0.f);
    }
    __syncthreads();                       // Cs16 complete

    // ---- GEMM 2 (A2 from Cs16, weights Wsb)
    f16x8 afrag2[4];
    {
        const int crow = wave * 16 + m16;
        #pragma unroll
        for (int kc = 0; kc < 4; ++kc)
            afrag2[kc] = *(const f16x8*)&Cs16[crow][quad * 8 + kc * 32];
    }
    #pragma unroll
    for (int np = 0; np < 8; np += 2) {
        f32x4 a0 = {0.f, 0.f, 0.f, 0.f};
        f32x4 a1 = {0.f, 0.f, 0.f, 0.f};
        const _Float16* b0 = &Wsb[np * 16 + m16][quad * 8];
        const _Float16* b1 = &Wsb[(np + 1) * 16 + m16][quad * 8];
        #pragma unroll
        for (int kc = 0; kc < 4; ++kc) {
            f16x8 f0 = *(const f16x8*)(b0 + kc * 32);
            f16x8 f1 = *(const f16x8*)(b1 + kc * 32);
            a0 = __builtin_amdgcn_mfma_f32_16x16x32_f16(afrag2[kc], f0, a0, 0, 0, 0);
            a1 = __builtin_amdgcn_mfma_f32_16x16x32_f16(afrag2[kc], f1, a1, 0, 0, 0);
        }
        accs[np] = a0; accs[np + 1] = a1;
    }
    __syncthreads();                       // all Cs16/Wsb reads done

    // epilogue fp32 C over whole region
    #pragma unroll
    for (int np = 0; np < 8; ++np) {
        int c = np * 16 + m16;
        float bb = biasb[c];
        #pragma unroll
        for (int r = 0; r < 4; ++r)
            CsF[wave * 16 + quad * 4 + r][c] = accs[np][r] + bb;
    }
    __syncthreads();                       // CsF complete

    const int s4 = t & 31;                 // float4 col
    const int rb = t >> 5;                 // 16 row groups
    float lsum[4] = {}, lsq[4] = {};
    #pragma unroll
    for (int i = 0; i < 8; ++i) {
        int r = rb + i * 16;
        int row = row0 + r;
        float4 v = *(const float4*)&CsF[r][s4 * 4];
        if (row < NNODES) {
            if (Cb) {
                ushort4 o;
                o.x = f2h_bits(v.x); o.y = f2h_bits(v.y);
                o.z = f2h_bits(v.z); o.w = f2h_bits(v.w);
                ((ushort4*)Cb)[(long)row * 32 + s4] = o;
            }
            if (Cf) ((float4*)Cf)[(long)row * 32 + s4] = v;
            lsum[0] += v.x; lsum[1] += v.y; lsum[2] += v.z; lsum[3] += v.w;
            lsq[0] = fmaf(v.x, v.x, lsq[0]);
            lsq[1] = fmaf(v.y, v.y, lsq[1]);
            lsq[2] = fmaf(v.z, v.z, lsq[2]);
            lsq[3] = fmaf(v.w, v.w, lsq[3]);
        }
    }
    __syncthreads();                       // CsF reads done before redp overlay

    #pragma unroll
    for (int j = 0; j < 4; ++j) {
        redp[(0 * 16 + rb) * 128 + s4 * 4 + j] = lsum[j];
        redp[(1 * 16 + rb) * 128 + s4 * 4 + j] = lsq[j];
    }
    __syncthreads();
    if (t < 128) {
        float s = 0.f, q = 0.f;
        #pragma unroll
        for (int g = 0; g < 16; ++g) {
            s += redp[g * 128 + t];
            q += redp[(16 + g) * 128 + t];
        }
        const int cls = blockIdx.x & 7;            // XCD-classed stats region
        atomicAdd(&out_sum[cls * 128 + t], s);
        atomicAdd(&out_sq[cls * 128 + t],  q);
    }
}

// ================= BN fold (sums the 8 class copies) =================
__global__ void bn_prep(const float* __restrict__ ssum, const float* __restrict__ ssq,
                        const float* __restrict__ gamma, const float* __restrict__ beta,
                        float* __restrict__ scale, float* __restrict__ shift)
{
    int c = threadIdx.x;
    float s = 0.f, q = 0.f;
    #pragma unroll
    for (int g = 0; g < 8; ++g) {
        s += ssum[g * 128 + c];
        q += ssq[g * 128 + c];
    }
    const float invN = 1.0f / (float)NNODES;
    float m = s * invN;
    float var = fmaf(-m, m, q * invN);
    float rs = rsqrtf(var + 1e-5f);
    float sc = gamma[c] * rs;
    scale[c] = sc;
    shift[c] = beta[c] - m * sc;
}

// ========== projection + softmax, BN2+ReLU fused on load ==========
__global__ __launch_bounds__(256) void out_proj_softmax(
    const float* __restrict__ H, const float* __restrict__ Wout,
    const float* __restrict__ scale, const float* __restrict__ shift,
    const float* __restrict__ log_tau,
    float* __restrict__ outS, float* __restrict__ outL)
{
    __shared__ float As[HD][20];
    const int t = threadIdx.x;
    const long row0 = (long)blockIdx.x * 16;

    #pragma unroll
    for (int i = 0; i < 8; ++i) {
        int idx = t + i * 256;
        int r = idx >> 7, cc = idx & 127;
        float v = H[(row0 + r) * HD + cc];
        As[cc][r] = fmaxf(fmaf(v, scale[cc], shift[cc]), 0.f);
    }
    __syncthreads();

    const int c = t & 63;
    const int g = t >> 6;
    float acc[4] = {};

    float wq[8];
    #pragma unroll
    for (int i = 0; i < 8; ++i) wq[i] = Wout[i * KOUT + c];

    #pragma unroll 1
    for (int kc = 0; kc < HD; kc += 8) {
        float wn[8];
        if (kc + 8 < HD) {
            #pragma unroll
            for (int i = 0; i < 8; ++i) wn[i] = Wout[(kc + 8 + i) * KOUT + c];
        }
        #pragma unroll
        for (int i = 0; i < 8; ++i) {
            float4 a = *(const float4*)&As[kc + i][g * 4];
            acc[0] = fmaf(a.x, wq[i], acc[0]);
            acc[1] = fmaf(a.y, wq[i], acc[1]);
            acc[2] = fmaf(a.z, wq[i], acc[2]);
            acc[3] = fmaf(a.w, wq[i], acc[3]);
        }
        if (kc + 8 < HD) {
            #pragma unroll
            for (int i = 0; i < 8; ++i) wq[i] = wn[i];
        }
    }

    float inv_tau = __expf(-log_tau[0]);
    #pragma unroll
    for (int i = 0; i < 4; ++i) {
        float z = acc[i] * inv_tau;
        float m = z;
        #pragma unroll
        for (int o = 32; o > 0; o >>= 1) m = fmaxf(m, __shfl_xor(m, o));
        float e = __expf(z - m);
        float s = e;
        #pragma unroll
        for (int o = 32; o > 0; o >>= 1) s += __shfl_xor(s, o);
        long oi = (row0 + g * 4 + i) * KOUT + c;
        outS[oi] = e / s;
        outL[oi] = acc[i];
    }
}

extern "C" void kernel_launch(void* const* d_in, const int* in_sizes, int n_in,
                              void* d_out, int out_size, void* d_ws, size_t ws_size,
                              hipStream_t stream)
{
    const float* x      = (const float*)d_in[0];
    const int*   ei     = (const int*)d_in[1];
    const float* W1a    = (const float*)d_in[2];
    const float* b1a    = (const float*)d_in[3];
    const float* W1b    = (const float*)d_in[4];
    const float* b1b    = (const float*)d_in[5];
    const float* eps1   = (const float*)d_in[6];
    const float* gamma1 = (const float*)d_in[7];
    const float* beta1  = (const float*)d_in[8];
    const float* W2a    = (const float*)d_in[9];
    const float* b2a    = (const float*)d_in[10];
    const float* W2b    = (const float*)d_in[11];
    const float* b2b    = (const float*)d_in[12];
    const float* eps2   = (const float*)d_in[13];
    const float* gamma2 = (const float*)d_in[14];
    const float* beta2  = (const float*)d_in[15];
    const float* Wout   = (const float*)d_in[16];
    const float* ltau   = (const float*)d_in[17];

    const size_t NB = (size_t)NNODES * HD;
    float* B0 = (float*)d_ws;
    float* B1 = B0 + NB;
    float* B2 = B1 + NB;
    float* ST = B2 + NB;             // stats: 4 x [8][128] classed + scales
    float* sum1 = ST, *sq1 = ST + 1024, *sum2 = ST + 2048, *sq2 = ST + 3072;
    float* scale1 = ST + 4096, *shift1 = ST + 4224;
    float* scale2 = ST + 4352, *shift2 = ST + 4480;

    unsigned short* xh  = (unsigned short*)B2;   // f16 x (CSR + gather1)
    unsigned short* h0h = (unsigned short*)B0;   // gather1 out; mlp1 in-place -> hh
    unsigned short* hh  = (unsigned short*)B0;   // h1 f16
    unsigned short* h2h = (unsigned short*)B2;   // gather2 out

    int* I0        = (int*)(ST + 4608);
    int* deg       = I0;
    int* incl      = I0 + 50048;
    int* row_start = I0 + 2 * 50048;
    int* cur       = I0 + 3 * 50048;
    int* bsum      = I0 + 4 * 50048;
    int* col       = bsum + 256;                // NEDGES ints
    unsigned short* wt1a = (unsigned short*)(col + NEDGES);  // 4 x 128x128 f16
    unsigned short* wt1b = wt1a + HD * HD;
    unsigned short* wt2a = wt1b + HD * HD;
    unsigned short* wt2b = wt2a + HD * HD;

    const int SCAN_BLKS = (NNODES + 255) / 256;   // 196
    const int GEMM_BLKS = (NNODES + 127) / 128;   // 391 (M=128 tile)
    const int GATH_BLKS = (NNODES + 31) / 32;     // 1563 (32 nodes/block)

    hipMemsetAsync(ST, 0, 4096 * sizeof(float), stream);
    hipMemsetAsync(deg, 0, NNODES * sizeof(int), stream);
    prep_all<<<HIST_BLKS + 6506, 256, 0, stream>>>(x, xh, W1a, W1b, W2a, W2b,
                                                   wt1a, wt1b, wt2a, wt2b, ei, deg);
    scan_a<<<SCAN_BLKS, 256, 0, stream>>>(deg, incl, bsum);
    scan_c<<<SCAN_BLKS, 256, 0, stream>>>(deg, incl, bsum, row_start, cur);
    edge_fill<<<2048, 256, 0, stream>>>(ei, cur, col);

    // ---- layer 1
    gin_gather_w<false><<<GATH_BLKS, 256, 0, stream>>>(
        xh, col, row_start, cur, eps1, nullptr, nullptr, h0h);
    mlp_mfma<<<GEMM_BLKS, 512, 0, stream>>>(
        h0h, wt1a, b1a, wt1b, b1b, hh, nullptr, sum1, sq1);
    bn_prep<<<1, 128, 0, stream>>>(sum1, sq1, gamma1, beta1, scale1, shift1);

    // ---- layer 2 (BN1+ReLU fused into gather reads)
    gin_gather_w<true><<<GATH_BLKS, 256, 0, stream>>>(
        hh, col, row_start, cur, eps2, scale1, shift1, h2h);
    mlp_mfma<<<GEMM_BLKS, 512, 0, stream>>>(
        h2h, wt2a, b2a, wt2b, b2b, nullptr, B1, sum2, sq2);
    bn_prep<<<1, 128, 0, stream>>>(sum2, sq2, gamma2, beta2, scale2, shift2);

    // ---- projection + softmax (BN2+ReLU fused on load)
    out_proj_softmax<<<NNODES / 16, 256, 0, stream>>>(
        B1, Wout, scale2, shift2, ltau,
        (float*)d_out, (float*)d_out + (size_t)NNODES * KOUT);
}

// Round 14
// 288.659 us; speedup vs baseline: 1.0722x; 1.0284x over previous
//
#include <hip/hip_runtime.h>
#include <hip/hip_fp16.h>

// GIN 2-layer + BN + softmax pipeline for MI355X. All tensors fp32; edges int32.
// R25: R24 + int4-vectorized edge streams. edge_fill surfaced at 39.9us with
// FETCH=25.4MB (8x dst re-read, cold HBM -- harness fills flush L3), 18% HBM,
// 4.8% VALU = load-ISSUE bound. int4 loads (4 edges/thread) for dst+src cut
// load instrs ~4-5x; src read unconditional (88% of its lines fetched anyway).
// Same class-windowed XCD-local atomics. prep_all hist dst stream also int4.
// Chunks 3200 edges (250 x 8 = 2000 blocks).
// KEEP: everything else = R24/R21 converged structure.
//
// Workspace timeline (B0/B1/B2 = 25.6 MB fp32 regions; h* = f16 aliases):
//   prep_all: hist->deg ; xh=(u16*)B2 <- x ; wt* <- W*
//   gather1:  reads xh(B2)    -> h0h=(u16*)B0
//   mlp1:     A=h0h(B0)       -> hh=(u16*)B0 IN-PLACE + stats1 (8-class)
//   gather2:  reads hh(B0)+BN -> h2h=(u16*)B2 (kills xh, OK)
//   mlp2:     A=h2h(B2)       -> h2 fp32 = B1 + stats2 (8-class)
//   out_proj: reads B1 (+BN2 fused)

#define NNODES 50000
#define NEDGES 800000
#define HD 128
#define KOUT 64
#define NCLS 8
#define CLSW 6250            // nodes per class window (NNODES/NCLS)
#define HIST_BLKS 512        // 64 edge-chunks x 8 classes
#define EF_CHUNK 3200        // edge_fill chunk (250 chunks x 8 classes)

typedef __attribute__((ext_vector_type(8))) _Float16 f16x8;
typedef __attribute__((ext_vector_type(4))) float f32x4;

__device__ __forceinline__ unsigned short f2h_bits(float f) {   // RNE f32->f16
    _Float16 h = (_Float16)f;
    return __builtin_bit_cast(unsigned short, h);
}
__device__ __forceinline__ f16x8 h8_relu(f16x8 v) {
    #pragma unroll
    for (int i = 0; i < 8; ++i) v[i] = (v[i] > (_Float16)0.f) ? v[i] : (_Float16)0.f;
    return v;
}

// ===== prep: classed deg histogram (bid<512) | x -> f16 | weight transposes =====
__global__ __launch_bounds__(256) void prep_all(
    const float* __restrict__ x, unsigned short* __restrict__ xh,
    const float* __restrict__ W1a, const float* __restrict__ W1b,
    const float* __restrict__ W2a, const float* __restrict__ W2b,
    unsigned short* __restrict__ wt1a, unsigned short* __restrict__ wt1b,
    unsigned short* __restrict__ wt2a, unsigned short* __restrict__ wt2b,
    const int* __restrict__ ei, int* __restrict__ deg)
{
    __shared__ int h[CLSW];                 // 25000 B (hist blocks only)
    int bid = blockIdx.x;
    if (bid < HIST_BLKS) {                  // classed LDS histogram, int4 dst
        const int cls = bid & 7;
        const int lo = cls * CLSW;
        const int e0 = (bid >> 3) * 12500;  // 64 chunks x 12500 = NEDGES
        for (int i = threadIdx.x; i < CLSW; i += 256) h[i] = 0;
        __syncthreads();
        const int4* d4p = (const int4*)(ei + NEDGES) + (e0 >> 2);   // 3125 int4
        for (int i = threadIdx.x; i < 3125; i += 256) {
            int4 d = d4p[i];
            unsigned a0 = (unsigned)(d.x - lo), a1 = (unsigned)(d.y - lo);
            unsigned a2 = (unsigned)(d.z - lo), a3 = (unsigned)(d.w - lo);
            if (a0 < (unsigned)CLSW) atomicAdd(&h[a0], 1);
            if (a1 < (unsigned)CLSW) atomicAdd(&h[a1], 1);
            if (a2 < (unsigned)CLSW) atomicAdd(&h[a2], 1);
            if (a3 < (unsigned)CLSW) atomicAdd(&h[a3], 1);
        }
        __syncthreads();
        for (int i = threadIdx.x; i < CLSW; i += 256) {
            int v = h[i];
            if (v) atomicAdd(&deg[lo + i], v);  // coalesced, XCD-local
        }
    } else if (bid < HIST_BLKS + 6250) {    // x -> f16 (float4 per thread)
        int i = (bid - HIST_BLKS) * 256 + threadIdx.x;
        float4 v = ((const float4*)x)[i];
        ushort4 o;
        o.x = f2h_bits(v.x); o.y = f2h_bits(v.y);
        o.z = f2h_bits(v.z); o.w = f2h_bits(v.w);
        ((ushort4*)xh)[i] = o;
    } else {                                // Wt[n][k] = f16(W[k][n])
        int wb = bid - (HIST_BLKS + 6250);  // 0..255
        int w = wb >> 6;
        int idx = (wb & 63) * 256 + threadIdx.x;   // 0..16383
        int n = idx >> 7, k = idx & 127;
        const float* W = (w == 0) ? W1a : (w == 1) ? W1b : (w == 2) ? W2a : W2b;
        unsigned short* Wt = (w == 0) ? wt1a : (w == 1) ? wt1b : (w == 2) ? wt2a : wt2b;
        Wt[idx] = f2h_bits(W[k * HD + n]);
    }
}

// ================= CSR build =================
__global__ __launch_bounds__(256) void scan_a(
    const int* __restrict__ deg, int* __restrict__ incl, int* __restrict__ bsum)
{
    __shared__ int s[256];
    int t = threadIdx.x, idx = blockIdx.x * 256 + t;
    int v = (idx < NNODES) ? deg[idx] : 0;
    s[t] = v; __syncthreads();
    #pragma unroll
    for (int off = 1; off < 256; off <<= 1) {
        int tmp = (t >= off) ? s[t - off] : 0;
        __syncthreads();
        s[t] += tmp;
        __syncthreads();
    }
    if (idx < NNODES) incl[idx] = s[t];
    if (t == 255) bsum[blockIdx.x] = s[255];
}

// scan_c with scan_b folded in: block offset = reduce(bsum[0..b-1])
__global__ __launch_bounds__(256) void scan_c(
    const int* __restrict__ deg, const int* __restrict__ incl,
    const int* __restrict__ bsum,
    int* __restrict__ row_start, int* __restrict__ cur)
{
    __shared__ int s[256];
    int b = blockIdx.x, t = threadIdx.x;
    int p = 0;
    for (int i = t; i < b; i += 256) p += bsum[i];
    s[t] = p; __syncthreads();
    #pragma unroll
    for (int off = 128; off > 0; off >>= 1) {
        if (t < off) s[t] += s[t + off];
        __syncthreads();
    }
    int off0 = s[0];
    int idx = b * 256 + t;
    if (idx >= NNODES) return;
    int ex = incl[idx] - deg[idx] + off0;
    row_start[idx] = ex;
    cur[idx] = ex;
}

// XCD-partitioned fill, int4 streams: 250 chunks x 8 classes; class =
// blockIdx&7 owns one 400KB col window -> single-L2 write accumulation.
// dst+src both read as int4 (4 edges/thread/iter): ~4-5x fewer load instrs.
__global__ __launch_bounds__(256) void edge_fill(
    const int* __restrict__ ei, int* __restrict__ cur, int* __restrict__ col)
{
    const int cls = blockIdx.x & 7;
    const int e0 = (blockIdx.x >> 3) * EF_CHUNK;
    const int4* d4p = (const int4*)(ei + NEDGES) + (e0 >> 2);
    const int4* s4p = (const int4*)ei + (e0 >> 2);
    for (int i = threadIdx.x; i < EF_CHUNK / 4; i += 256) {
        int4 d = d4p[i];
        int4 s = s4p[i];
        if (d.x / CLSW == cls) { int p = atomicAdd(&cur[d.x], 1); col[p] = s.x; }
        if (d.y / CLSW == cls) { int p = atomicAdd(&cur[d.y], 1); col[p] = s.y; }
        if (d.z / CLSW == cls) { int p = atomicAdd(&cur[d.z], 1); col[p] = s.z; }
        if (d.w / CLSW == cls) { int p = atomicAdd(&cur[d.w], 1); col[p] = s.w; }
    }
}

// ========== gather (f16 in/out), 16 lanes/node x 16B loads, pk-f16 math ==========
// 2 serial nodes/group (32 nodes/block, grid 1563 = full TLP) + 8-deep load
// unroll (ILP for the L3-latency-bound random reads).
template<bool BN>
__global__ __launch_bounds__(256) void gin_gather_w(
    const unsigned short* __restrict__ Xh, const int* __restrict__ col,
    const int* __restrict__ rs, const int* __restrict__ re,
    const float* __restrict__ eps,
    const float* __restrict__ scale, const float* __restrict__ shift,
    unsigned short* __restrict__ H0h)
{
    const int t = threadIdx.x;
    const int g = t >> 4;            // 16 groups
    const int lane = t & 15;         // 16B per lane -> 8 feats
    const f16x8* X8 = (const f16x8*)Xh;        // 16 f16x8 per row
    const float alphaf = 1.f + eps[0];

    f16x8 sc8, sh8, al8;
    #pragma unroll
    for (int i = 0; i < 8; ++i) al8[i] = (_Float16)alphaf;
    if (BN) {
        #pragma unroll
        for (int i = 0; i < 8; ++i) {
            sc8[i] = (_Float16)scale[lane * 8 + i];
            sh8[i] = (_Float16)shift[lane * 8 + i];
        }
    }

    #pragma unroll 1
    for (int nn = 0; nn < 2; ++nn) {
        int node = blockIdx.x * 32 + nn * 16 + g;
        if (node >= NNODES) continue;

        f16x8 acc = X8[(long)node * 16 + lane];
        if (BN) acc = h8_relu(acc * sc8 + sh8);
        acc = acc * al8;

        int j = rs[node], end = re[node];
        for (; j + 7 < end; j += 8) {
            int c0 = col[j],     c1 = col[j + 1], c2 = col[j + 2], c3 = col[j + 3];
            int c4 = col[j + 4], c5 = col[j + 5], c6 = col[j + 6], c7 = col[j + 7];
            f16x8 u0 = X8[(long)c0 * 16 + lane];
            f16x8 u1 = X8[(long)c1 * 16 + lane];
            f16x8 u2 = X8[(long)c2 * 16 + lane];
            f16x8 u3 = X8[(long)c3 * 16 + lane];
            f16x8 u4 = X8[(long)c4 * 16 + lane];
            f16x8 u5 = X8[(long)c5 * 16 + lane];
            f16x8 u6 = X8[(long)c6 * 16 + lane];
            f16x8 u7 = X8[(long)c7 * 16 + lane];
            if (BN) {
                u0 = h8_relu(u0 * sc8 + sh8); u1 = h8_relu(u1 * sc8 + sh8);
                u2 = h8_relu(u2 * sc8 + sh8); u3 = h8_relu(u3 * sc8 + sh8);
                u4 = h8_relu(u4 * sc8 + sh8); u5 = h8_relu(u5 * sc8 + sh8);
                u6 = h8_relu(u6 * sc8 + sh8); u7 = h8_relu(u7 * sc8 + sh8);
            }
            acc += ((u0 + u1) + (u2 + u3)) + ((u4 + u5) + (u6 + u7));
        }
        for (; j + 3 < end; j += 4) {
            f16x8 u0 = X8[(long)col[j]     * 16 + lane];
            f16x8 u1 = X8[(long)col[j + 1] * 16 + lane];
            f16x8 u2 = X8[(long)col[j + 2] * 16 + lane];
            f16x8 u3 = X8[(long)col[j + 3] * 16 + lane];
            if (BN) {
                u0 = h8_relu(u0 * sc8 + sh8); u1 = h8_relu(u1 * sc8 + sh8);
                u2 = h8_relu(u2 * sc8 + sh8); u3 = h8_relu(u3 * sc8 + sh8);
            }
            acc += (u0 + u1) + (u2 + u3);
        }
        for (; j < end; ++j) {
            f16x8 u = X8[(long)col[j] * 16 + lane];
            if (BN) u = h8_relu(u * sc8 + sh8);
            acc += u;
        }

        ((f16x8*)H0h)[(long)node * 16 + lane] = acc;
    }
}

// ========== fused MLP: C = (ReLU(A@Wa + ba))@Wb + bb, + per-col stats ==========
// M=128 tile, 512 threads (8 waves). LDS: Wsa(34816)+Wsb(34816)=69632 B.
// Cs16 f16[128][136] overlays Wsa after GEMM1; CsF fp32[128][132] overlays the
// whole region after GEMM2; redp (16KB) overlays base after CsF reads.
// Stats atomics XCD-classed: out_sum/out_sq are [8][128]; class = blockIdx&7.
__global__ __launch_bounds__(512) void mlp_mfma(
    const unsigned short* __restrict__ A,      // [M][128] f16
    const unsigned short* __restrict__ Wta,    // [128][128] f16 N-major
    const float* __restrict__ biasa,
    const unsigned short* __restrict__ Wtb,
    const float* __restrict__ biasb,
    unsigned short* __restrict__ Cb,           // optional f16 out
    float* __restrict__ Cf,                    // optional fp32 out
    float* __restrict__ out_sum, float* __restrict__ out_sq)
{
    __shared__ float4 smem4[69632 / 16];
    char* smem = (char*)smem4;
    _Float16 (*Wsa)[136]  = (_Float16(*)[136])smem;            // 128x136 f16
    _Float16 (*Wsb)[136]  = (_Float16(*)[136])(smem + 34816);  // 128x136 f16
    _Float16 (*Cs16)[136] = (_Float16(*)[136])smem;            // overlays Wsa
    float (*CsF)[132]     = (float(*)[132])smem;               // 128x132 f32 = 67584
    float* redp           = (float*)smem;                      // 2*16*128 f32 = 16KB

    const int t = threadIdx.x;
    const int wave = t >> 6, lane = t & 63;
    const int m16 = lane & 15, quad = lane >> 4;
    const int row0 = blockIdx.x * 128;
    const int arow = row0 + wave * 16 + m16;

    #pragma unroll
    for (int i = 0; i < 4; ++i) {
        int idx = t + i * 512;
        int r = idx >> 4, s = idx & 15;
        *(float4*)&Wsa[r][s * 8] = ((const float4*)Wta)[idx];
        *(float4*)&Wsb[r][s * 8] = ((const float4*)Wtb)[idx];
    }

    f16x8 afrag[4];
    if (arow < NNODES) {
        const _Float16* ar = (const _Float16*)A + (long)arow * HD + quad * 8;
        #pragma unroll
        for (int kc = 0; kc < 4; ++kc)
            afrag[kc] = *(const f16x8*)(ar + kc * 32);
    } else {
        #pragma unroll
        for (int kc = 0; kc < 4; ++kc)
            afrag[kc] = f16x8{0, 0, 0, 0, 0, 0, 0, 0};
    }
    __syncthreads();

    // ---- GEMM 1 (reads Wsa)
    f32x4 accs[8];
    #pragma unroll
    for (int np = 0; np < 8; np += 2) {
        f32x4 a0 = {0.f, 0.f, 0.f, 0.f};
        f32x4 a1 = {0.f, 0.f, 0.f, 0.f};
        const _Float16* b0 = &Wsa[np * 16 + m16][quad * 8];
        const _Float16* b1 = &Wsa[(np + 1) * 16 + m16][quad * 8];
        #pragma unroll
        for (int kc = 0; kc < 4; ++kc) {
            f16x8 f0 = *(const f16x8*)(b0 + kc * 32);
            f16x8 f1 = *(const f16x8*)(b1 + kc * 32);
            a0 = __builtin_amdgcn_mfma_f32_16x16x32_f16(afrag[kc], f0, a0, 0, 0, 0);
            a1 = __builtin_amdgcn_mfma_f32_16x16x32_f16(afrag[kc], f1, a1, 0, 0, 0);
        }
        accs[np] = a0; accs[np + 1] = a1;
    }
    __syncthreads();                       // all Wsa reads done

    // bias+ReLU -> f16 into Cs16 (overlays Wsa); rows disjoint per wave
    #pragma unroll
    for (int np = 0; np < 8; ++np) {
        int c = np * 16 + m16;
        float bb = biasa[c];
        #pragma unroll
        for (int r = 0; r < 4; ++r)
            Cs16[wave * 16 + quad * 4 + r][c] =
                (_Float16)fmaxf(accs[np][r] + bb, 0.f);
    }
    __syncthreads();                       // Cs16 complete

    // ---- GEMM 2 (A2 from Cs16, weights Wsb)
    f16x8 afrag2[4];
    {
        const int crow = wave * 16 + m16;
        #pragma unroll
        for (int kc = 0; kc < 4; ++kc)
            afrag2[kc] = *(const f16x8*)&Cs16[crow][quad * 8 + kc * 32];
    }
    #pragma unroll
    for (int np = 0; np < 8; np += 2) {
        f32x4 a0 = {0.f, 0.f, 0.f, 0.f};
        f32x4 a1 = {0.f, 0.f, 0.f, 0.f};
        const _Float16* b0 = &Wsb[np * 16 + m16][quad * 8];
        const _Float16* b1 = &Wsb[(np + 1) * 16 + m16][quad * 8];
        #pragma unroll
        for (int kc = 0; kc < 4; ++kc) {
            f16x8 f0 = *(const f16x8*)(b0 + kc * 32);
            f16x8 f1 = *(const f16x8*)(b1 + kc * 32);
            a0 = __builtin_amdgcn_mfma_f32_16x16x32_f16(afrag2[kc], f0, a0, 0, 0, 0);
            a1 = __builtin_amdgcn_mfma_f32_16x16x32_f16(afrag2[kc], f1, a1, 0, 0, 0);
        }
        accs[np] = a0; accs[np + 1] = a1;
    }
    __syncthreads();                       // all Cs16/Wsb reads done

    // epilogue fp32 C over whole region
    #pragma unroll
    for (int np = 0; np < 8; ++np) {
        int c = np * 16 + m16;
        float bb = biasb[c];
        #pragma unroll
        for (int r = 0; r < 4; ++r)
            CsF[wave * 16 + quad * 4 + r][c] = accs[np][r] + bb;
    }
    __syncthreads();                       // CsF complete

    const int s4 = t & 31;                 // float4 col
    const int rb = t >> 5;                 // 16 row groups
    float lsum[4] = {}, lsq[4] = {};
    #pragma unroll
    for (int i = 0; i < 8; ++i) {
        int r = rb + i * 16;
        int row = row0 + r;
        float4 v = *(const float4*)&CsF[r][s4 * 4];
        if (row < NNODES) {
            if (Cb) {
                ushort4 o;
                o.x = f2h_bits(v.x); o.y = f2h_bits(v.y);
                o.z = f2h_bits(v.z); o.w = f2h_bits(v.w);
                ((ushort4*)Cb)[(long)row * 32 + s4] = o;
            }
            if (Cf) ((float4*)Cf)[(long)row * 32 + s4] = v;
            lsum[0] += v.x; lsum[1] += v.y; lsum[2] += v.z; lsum[3] += v.w;
            lsq[0] = fmaf(v.x, v.x, lsq[0]);
            lsq[1] = fmaf(v.y, v.y, lsq[1]);
            lsq[2] = fmaf(v.z, v.z, lsq[2]);
            lsq[3] = fmaf(v.w, v.w, lsq[3]);
        }
    }
    __syncthreads();                       // CsF reads done before redp overlay

    #pragma unroll
    for (int j = 0; j < 4; ++j) {
        redp[(0 * 16 + rb) * 128 + s4 * 4 + j] = lsum[j];
        redp[(1 * 16 + rb) * 128 + s4 * 4 + j] = lsq[j];
    }
    __syncthreads();
    if (t < 128) {
        float s = 0.f, q = 0.f;
        #pragma unroll
        for (int g = 0; g < 16; ++g) {
            s += redp[g * 128 + t];
            q += redp[(16 + g) * 128 + t];
        }
        const int cls = blockIdx.x & 7;            // XCD-classed stats region
        atomicAdd(&out_sum[cls * 128 + t], s);
        atomicAdd(&out_sq[cls * 128 + t],  q);
    }
}

// ================= BN fold (sums the 8 class copies) =================
__global__ void bn_prep(const float* __restrict__ ssum, const float* __restrict__ ssq,
                        const float* __restrict__ gamma, const float* __restrict__ beta,
                        float* __restrict__ scale, float* __restrict__ shift)
{
    int c = threadIdx.x;
    float s = 0.f, q = 0.f;
    #pragma unroll
    for (int g = 0; g < 8; ++g) {
        s += ssum[g * 128 + c];
        q += ssq[g * 128 + c];
    }
    const float invN = 1.0f / (float)NNODES;
    float m = s * invN;
    float var = fmaf(-m, m, q * invN);
    float rs = rsqrtf(var + 1e-5f);
    float sc = gamma[c] * rs;
    scale[c] = sc;
    shift[c] = beta[c] - m * sc;
}

// ========== projection + softmax, BN2+ReLU fused on load ==========
__global__ __launch_bounds__(256) void out_proj_softmax(
    const float* __restrict__ H, const float* __restrict__ Wout,
    const float* __restrict__ scale, const float* __restrict__ shift,
    const float* __restrict__ log_tau,
    float* __restrict__ outS, float* __restrict__ outL)
{
    __shared__ float As[HD][20];
    const int t = threadIdx.x;
    const long row0 = (long)blockIdx.x * 16;

    #pragma unroll
    for (int i = 0; i < 8; ++i) {
        int idx = t + i * 256;
        int r = idx >> 7, cc = idx & 127;
        float v = H[(row0 + r) * HD + cc];
        As[cc][r] = fmaxf(fmaf(v, scale[cc], shift[cc]), 0.f);
    }
    __syncthreads();

    const int c = t & 63;
    const int g = t >> 6;
    float acc[4] = {};

    float wq[8];
    #pragma unroll
    for (int i = 0; i < 8; ++i) wq[i] = Wout[i * KOUT + c];

    #pragma unroll 1
    for (int kc = 0; kc < HD; kc += 8) {
        float wn[8];
        if (kc + 8 < HD) {
            #pragma unroll
            for (int i = 0; i < 8; ++i) wn[i] = Wout[(kc + 8 + i) * KOUT + c];
        }
        #pragma unroll
        for (int i = 0; i < 8; ++i) {
            float4 a = *(const float4*)&As[kc + i][g * 4];
            acc[0] = fmaf(a.x, wq[i], acc[0]);
            acc[1] = fmaf(a.y, wq[i], acc[1]);
            acc[2] = fmaf(a.z, wq[i], acc[2]);
            acc[3] = fmaf(a.w, wq[i], acc[3]);
        }
        if (kc + 8 < HD) {
            #pragma unroll
            for (int i = 0; i < 8; ++i) wq[i] = wn[i];
        }
    }

    float inv_tau = __expf(-log_tau[0]);
    #pragma unroll
    for (int i = 0; i < 4; ++i) {
        float z = acc[i] * inv_tau;
        float m = z;
        #pragma unroll
        for (int o = 32; o > 0; o >>= 1) m = fmaxf(m, __shfl_xor(m, o));
        float e = __expf(z - m);
        float s = e;
        #pragma unroll
        for (int o = 32; o > 0; o >>= 1) s += __shfl_xor(s, o);
        long oi = (row0 + g * 4 + i) * KOUT + c;
        outS[oi] = e / s;
        outL[oi] = acc[i];
    }
}

extern "C" void kernel_launch(void* const* d_in, const int* in_sizes, int n_in,
                              void* d_out, int out_size, void* d_ws, size_t ws_size,
                              hipStream_t stream)
{
    const float* x      = (const float*)d_in[0];
    const int*   ei     = (const int*)d_in[1];
    const float* W1a    = (const float*)d_in[2];
    const float* b1a    = (const float*)d_in[3];
    const float* W1b    = (const float*)d_in[4];
    const float* b1b    = (const float*)d_in[5];
    const float* eps1   = (const float*)d_in[6];
    const float* gamma1 = (const float*)d_in[7];
    const float* beta1  = (const float*)d_in[8];
    const float* W2a    = (const float*)d_in[9];
    const float* b2a    = (const float*)d_in[10];
    const float* W2b    = (const float*)d_in[11];
    const float* b2b    = (const float*)d_in[12];
    const float* eps2   = (const float*)d_in[13];
    const float* gamma2 = (const float*)d_in[14];
    const float* beta2  = (const float*)d_in[15];
    const float* Wout   = (const float*)d_in[16];
    const float* ltau   = (const float*)d_in[17];

    const size_t NB = (size_t)NNODES * HD;
    float* B0 = (float*)d_ws;
    float* B1 = B0 + NB;
    float* B2 = B1 + NB;
    float* ST = B2 + NB;             // stats: 4 x [8][128] classed + scales
    float* sum1 = ST, *sq1 = ST + 1024, *sum2 = ST + 2048, *sq2 = ST + 3072;
    float* scale1 = ST + 4096, *shift1 = ST + 4224;
    float* scale2 = ST + 4352, *shift2 = ST + 4480;

    unsigned short* xh  = (unsigned short*)B2;   // f16 x (CSR + gather1)
    unsigned short* h0h = (unsigned short*)B0;   // gather1 out; mlp1 in-place -> hh
    unsigned short* hh  = (unsigned short*)B0;   // h1 f16
    unsigned short* h2h = (unsigned short*)B2;   // gather2 out

    int* I0        = (int*)(ST + 4608);
    int* deg       = I0;
    int* incl      = I0 + 50048;
    int* row_start = I0 + 2 * 50048;
    int* cur       = I0 + 3 * 50048;
    int* bsum      = I0 + 4 * 50048;
    int* col       = bsum + 256;                // NEDGES ints
    unsigned short* wt1a = (unsigned short*)(col + NEDGES);  // 4 x 128x128 f16
    unsigned short* wt1b = wt1a + HD * HD;
    unsigned short* wt2a = wt1b + HD * HD;
    unsigned short* wt2b = wt2a + HD * HD;

    const int SCAN_BLKS = (NNODES + 255) / 256;   // 196
    const int GEMM_BLKS = (NNODES + 127) / 128;   // 391 (M=128 tile)
    const int GATH_BLKS = (NNODES + 31) / 32;     // 1563 (32 nodes/block)
    const int EF_BLKS   = (NEDGES / EF_CHUNK) * 8; // 250 chunks x 8 classes

    hipMemsetAsync(ST, 0, 4096 * sizeof(float), stream);
    hipMemsetAsync(deg, 0, NNODES * sizeof(int), stream);
    prep_all<<<HIST_BLKS + 6506, 256, 0, stream>>>(x, xh, W1a, W1b, W2a, W2b,
                                                   wt1a, wt1b, wt2a, wt2b, ei, deg);
    scan_a<<<SCAN_BLKS, 256, 0, stream>>>(deg, incl, bsum);
    scan_c<<<SCAN_BLKS, 256, 0, stream>>>(deg, incl, bsum, row_start, cur);
    edge_fill<<<EF_BLKS, 256, 0, stream>>>(ei, cur, col);

    // ---- layer 1
    gin_gather_w<false><<<GATH_BLKS, 256, 0, stream>>>(
        xh, col, row_start, cur, eps1, nullptr, nullptr, h0h);
    mlp_mfma<<<GEMM_BLKS, 512, 0, stream>>>(
        h0h, wt1a, b1a, wt1b, b1b, hh, nullptr, sum1, sq1);
    bn_prep<<<1, 128, 0, stream>>>(sum1, sq1, gamma1, beta1, scale1, shift1);

    // ---- layer 2 (BN1+ReLU fused into gather reads)
    gin_gather_w<true><<<GATH_BLKS, 256, 0, stream>>>(
        hh, col, row_start, cur, eps2, scale1, shift1, h2h);
    mlp_mfma<<<GEMM_BLKS, 512, 0, stream>>>(
        h2h, wt2a, b2a, wt2b, b2b, nullptr, B1, sum2, sq2);
    bn_prep<<<1, 128, 0, stream>>>(sum2, sq2, gamma2, beta2, scale2, shift2);

    // ---- projection + softmax (BN2+ReLU fused on load)
    out_proj_softmax<<<NNODES / 16, 256, 0, stream>>>(
        B1, Wout, scale2, shift2, ltau,
        (float*)d_out, (float*)d_out + (size_t)NNODES * KOUT);
}

// Round 15
// 272.012 us; speedup vs baseline: 1.1378x; 1.0612x over previous
//
#include <hip/hip_runtime.h>
#include <hip/hip_fp16.h>

// GIN 2-layer + BN + softmax pipeline for MI355X. All tensors fp32; edges int32.
// R26: edge_fill WITHOUT global atomics. R25 proved edge_fill (41us) is not
// load-issue (int4 null), not BW (17%), not VALU (4%) -> it's the 800K
// returning atomicAdd(&cur[dst]) round-trips serializing at L2 lines.
// Counting-sort positioning instead: prep_all hist blocks store per-chunk
// window counts to cnt[64][50048]; cscan prefix-sums over chunks (in-place,
// -> per-chunk base) + produces deg; edge_fill computes slot = rs[d] +
// cnt[chunk][d] + LDS-rank (25KB class window, LDS atomics ~free). No cur.
// KEEP: everything else = R25 (best 288.7us).
//
// Workspace timeline (B0/B1/B2 = 25.6 MB fp32 regions; h* = f16 aliases):
//   prep_all: chunk-hists->cnt ; xh=(u16*)B2 <- x ; wt* <- W*
//   cscan:    cnt prefix over chunks -> bases, deg
//   gather1:  reads xh(B2)    -> h0h=(u16*)B0
//   mlp1:     A=h0h(B0)       -> hh=(u16*)B0 IN-PLACE + stats1 (8-class)
//   gather2:  reads hh(B0)+BN -> h2h=(u16*)B2 (kills xh, OK)
//   mlp2:     A=h2h(B2)       -> h2 fp32 = B1 + stats2 (8-class)
//   out_proj: reads B1 (+BN2 fused)

#define NNODES 50000
#define NEDGES 800000
#define HD 128
#define KOUT 64
#define NCLS 8
#define CLSW 6250            // nodes per class window (NNODES/NCLS)
#define HIST_BLKS 512        // 64 edge-chunks x 8 classes
#define NCHUNK 64
#define CH_E 12500           // edges per chunk
#define NODE_PAD 50048       // padded node stride for cnt rows

typedef __attribute__((ext_vector_type(8))) _Float16 f16x8;
typedef __attribute__((ext_vector_type(4))) float f32x4;

__device__ __forceinline__ unsigned short f2h_bits(float f) {   // RNE f32->f16
    _Float16 h = (_Float16)f;
    return __builtin_bit_cast(unsigned short, h);
}
__device__ __forceinline__ f16x8 h8_relu(f16x8 v) {
    #pragma unroll
    for (int i = 0; i < 8; ++i) v[i] = (v[i] > (_Float16)0.f) ? v[i] : (_Float16)0.f;
    return v;
}

// ===== prep: per-chunk classed hist -> cnt | x -> f16 | weight transposes =====
__global__ __launch_bounds__(256) void prep_all(
    const float* __restrict__ x, unsigned short* __restrict__ xh,
    const float* __restrict__ W1a, const float* __restrict__ W1b,
    const float* __restrict__ W2a, const float* __restrict__ W2b,
    unsigned short* __restrict__ wt1a, unsigned short* __restrict__ wt1b,
    unsigned short* __restrict__ wt2a, unsigned short* __restrict__ wt2b,
    const int* __restrict__ ei, int* __restrict__ cnt)
{
    __shared__ int h[CLSW];                 // 25000 B (hist blocks only)
    int bid = blockIdx.x;
    if (bid < HIST_BLKS) {                  // classed LDS histogram, int4 dst
        const int cls = bid & 7;
        const int chunk = bid >> 3;
        const int lo = cls * CLSW;
        const int e0 = chunk * CH_E;
        for (int i = threadIdx.x; i < CLSW; i += 256) h[i] = 0;
        __syncthreads();
        const int4* d4p = (const int4*)(ei + NEDGES) + (e0 >> 2);   // 3125 int4
        for (int i = threadIdx.x; i < CH_E / 4; i += 256) {
            int4 d = d4p[i];
            unsigned a0 = (unsigned)(d.x - lo), a1 = (unsigned)(d.y - lo);
            unsigned a2 = (unsigned)(d.z - lo), a3 = (unsigned)(d.w - lo);
            if (a0 < (unsigned)CLSW) atomicAdd(&h[a0], 1);
            if (a1 < (unsigned)CLSW) atomicAdd(&h[a1], 1);
            if (a2 < (unsigned)CLSW) atomicAdd(&h[a2], 1);
            if (a3 < (unsigned)CLSW) atomicAdd(&h[a3], 1);
        }
        __syncthreads();
        int* crow = cnt + chunk * NODE_PAD + lo;
        for (int i = threadIdx.x; i < CLSW; i += 256)
            crow[i] = h[i];                 // plain store; window owned by block
    } else if (bid < HIST_BLKS + 6250) {    // x -> f16 (float4 per thread)
        int i = (bid - HIST_BLKS) * 256 + threadIdx.x;
        float4 v = ((const float4*)x)[i];
        ushort4 o;
        o.x = f2h_bits(v.x); o.y = f2h_bits(v.y);
        o.z = f2h_bits(v.z); o.w = f2h_bits(v.w);
        ((ushort4*)xh)[i] = o;
    } else {                                // Wt[n][k] = f16(W[k][n])
        int wb = bid - (HIST_BLKS + 6250);  // 0..255
        int w = wb >> 6;
        int idx = (wb & 63) * 256 + threadIdx.x;   // 0..16383
        int n = idx >> 7, k = idx & 127;
        const float* W = (w == 0) ? W1a : (w == 1) ? W1b : (w == 2) ? W2a : W2b;
        unsigned short* Wt = (w == 0) ? wt1a : (w == 1) ? wt1b : (w == 2) ? wt2a : wt2b;
        Wt[idx] = f2h_bits(W[k * HD + n]);
    }
}

// ===== cscan: per-node prefix over 64 chunks (in-place) + deg =====
__global__ __launch_bounds__(256) void cscan(
    int* __restrict__ cnt, int* __restrict__ deg)
{
    int node = blockIdx.x * 256 + threadIdx.x;
    if (node >= NNODES) return;
    int* p = cnt + node;
    int run = 0;
    #pragma unroll 8
    for (int c = 0; c < NCHUNK; ++c) {
        int v = p[(long)c * NODE_PAD];
        p[(long)c * NODE_PAD] = run;
        run += v;
    }
    deg[node] = run;
}

// ================= CSR scan =================
__global__ __launch_bounds__(256) void scan_a(
    const int* __restrict__ deg, int* __restrict__ incl, int* __restrict__ bsum)
{
    __shared__ int s[256];
    int t = threadIdx.x, idx = blockIdx.x * 256 + t;
    int v = (idx < NNODES) ? deg[idx] : 0;
    s[t] = v; __syncthreads();
    #pragma unroll
    for (int off = 1; off < 256; off <<= 1) {
        int tmp = (t >= off) ? s[t - off] : 0;
        __syncthreads();
        s[t] += tmp;
        __syncthreads();
    }
    if (idx < NNODES) incl[idx] = s[t];
    if (t == 255) bsum[blockIdx.x] = s[255];
}

// scan_c: row_start + row_end (scan_b folded; no cur/atomics)
__global__ __launch_bounds__(256) void scan_c(
    const int* __restrict__ deg, const int* __restrict__ incl,
    const int* __restrict__ bsum,
    int* __restrict__ row_start, int* __restrict__ row_end)
{
    __shared__ int s[256];
    int b = blockIdx.x, t = threadIdx.x;
    int p = 0;
    for (int i = t; i < b; i += 256) p += bsum[i];
    s[t] = p; __syncthreads();
    #pragma unroll
    for (int off = 128; off > 0; off >>= 1) {
        if (t < off) s[t] += s[t + off];
        __syncthreads();
    }
    int off0 = s[0];
    int idx = b * 256 + t;
    if (idx >= NNODES) return;
    int inc = incl[idx];
    row_start[idx] = inc - deg[idx] + off0;
    row_end[idx] = inc + off0;
}

// XCD-partitioned fill, ATOMIC-FREE: 64 chunks x 8 classes. slot = rs[d] +
// cnt[chunk][d] (earlier-chunk base) + LDS rank within (chunk, class window).
__global__ __launch_bounds__(256) void edge_fill(
    const int* __restrict__ ei, const int* __restrict__ rs,
    const int* __restrict__ cnt, int* __restrict__ col)
{
    __shared__ int h[CLSW];
    const int cls = blockIdx.x & 7;
    const int chunk = blockIdx.x >> 3;
    const int lo = cls * CLSW;
    const int e0 = chunk * CH_E;
    const int* cb = cnt + chunk * NODE_PAD;
    for (int i = threadIdx.x; i < CLSW; i += 256) h[i] = 0;
    __syncthreads();
    const int4* d4p = (const int4*)(ei + NEDGES) + (e0 >> 2);
    const int4* s4p = (const int4*)ei + (e0 >> 2);
    for (int i = threadIdx.x; i < CH_E / 4; i += 256) {
        int4 d = d4p[i];
        int4 s = s4p[i];
        unsigned a0 = (unsigned)(d.x - lo), a1 = (unsigned)(d.y - lo);
        unsigned a2 = (unsigned)(d.z - lo), a3 = (unsigned)(d.w - lo);
        if (a0 < (unsigned)CLSW) {
            int r = atomicAdd(&h[a0], 1);
            col[rs[d.x] + cb[d.x] + r] = s.x;
        }
        if (a1 < (unsigned)CLSW) {
            int r = atomicAdd(&h[a1], 1);
            col[rs[d.y] + cb[d.y] + r] = s.y;
        }
        if (a2 < (unsigned)CLSW) {
            int r = atomicAdd(&h[a2], 1);
            col[rs[d.z] + cb[d.z] + r] = s.z;
        }
        if (a3 < (unsigned)CLSW) {
            int r = atomicAdd(&h[a3], 1);
            col[rs[d.w] + cb[d.w] + r] = s.w;
        }
    }
}

// ========== gather (f16 in/out), 16 lanes/node x 16B loads, pk-f16 math ==========
// 2 serial nodes/group (32 nodes/block, grid 1563 = full TLP) + 8-deep load
// unroll (ILP for the L3-latency-bound random reads).
template<bool BN>
__global__ __launch_bounds__(256) void gin_gather_w(
    const unsigned short* __restrict__ Xh, const int* __restrict__ col,
    const int* __restrict__ rs, const int* __restrict__ re,
    const float* __restrict__ eps,
    const float* __restrict__ scale, const float* __restrict__ shift,
    unsigned short* __restrict__ H0h)
{
    const int t = threadIdx.x;
    const int g = t >> 4;            // 16 groups
    const int lane = t & 15;         // 16B per lane -> 8 feats
    const f16x8* X8 = (const f16x8*)Xh;        // 16 f16x8 per row
    const float alphaf = 1.f + eps[0];

    f16x8 sc8, sh8, al8;
    #pragma unroll
    for (int i = 0; i < 8; ++i) al8[i] = (_Float16)alphaf;
    if (BN) {
        #pragma unroll
        for (int i = 0; i < 8; ++i) {
            sc8[i] = (_Float16)scale[lane * 8 + i];
            sh8[i] = (_Float16)shift[lane * 8 + i];
        }
    }

    #pragma unroll 1
    for (int nn = 0; nn < 2; ++nn) {
        int node = blockIdx.x * 32 + nn * 16 + g;
        if (node >= NNODES) continue;

        f16x8 acc = X8[(long)node * 16 + lane];
        if (BN) acc = h8_relu(acc * sc8 + sh8);
        acc = acc * al8;

        int j = rs[node], end = re[node];
        for (; j + 7 < end; j += 8) {
            int c0 = col[j],     c1 = col[j + 1], c2 = col[j + 2], c3 = col[j + 3];
            int c4 = col[j + 4], c5 = col[j + 5], c6 = col[j + 6], c7 = col[j + 7];
            f16x8 u0 = X8[(long)c0 * 16 + lane];
            f16x8 u1 = X8[(long)c1 * 16 + lane];
            f16x8 u2 = X8[(long)c2 * 16 + lane];
            f16x8 u3 = X8[(long)c3 * 16 + lane];
            f16x8 u4 = X8[(long)c4 * 16 + lane];
            f16x8 u5 = X8[(long)c5 * 16 + lane];
            f16x8 u6 = X8[(long)c6 * 16 + lane];
            f16x8 u7 = X8[(long)c7 * 16 + lane];
            if (BN) {
                u0 = h8_relu(u0 * sc8 + sh8); u1 = h8_relu(u1 * sc8 + sh8);
                u2 = h8_relu(u2 * sc8 + sh8); u3 = h8_relu(u3 * sc8 + sh8);
                u4 = h8_relu(u4 * sc8 + sh8); u5 = h8_relu(u5 * sc8 + sh8);
                u6 = h8_relu(u6 * sc8 + sh8); u7 = h8_relu(u7 * sc8 + sh8);
            }
            acc += ((u0 + u1) + (u2 + u3)) + ((u4 + u5) + (u6 + u7));
        }
        for (; j + 3 < end; j += 4) {
            f16x8 u0 = X8[(long)col[j]     * 16 + lane];
            f16x8 u1 = X8[(long)col[j + 1] * 16 + lane];
            f16x8 u2 = X8[(long)col[j + 2] * 16 + lane];
            f16x8 u3 = X8[(long)col[j + 3] * 16 + lane];
            if (BN) {
                u0 = h8_relu(u0 * sc8 + sh8); u1 = h8_relu(u1 * sc8 + sh8);
                u2 = h8_relu(u2 * sc8 + sh8); u3 = h8_relu(u3 * sc8 + sh8);
            }
            acc += (u0 + u1) + (u2 + u3);
        }
        for (; j < end; ++j) {
            f16x8 u = X8[(long)col[j] * 16 + lane];
            if (BN) u = h8_relu(u * sc8 + sh8);
            acc += u;
        }

        ((f16x8*)H0h)[(long)node * 16 + lane] = acc;
    }
}

// ========== fused MLP: C = (ReLU(A@Wa + ba))@Wb + bb, + per-col stats ==========
// M=128 tile, 512 threads (8 waves). LDS: Wsa(34816)+Wsb(34816)=69632 B.
// Cs16 f16[128][136] overlays Wsa after GEMM1; CsF fp32[128][132] overlays the
// whole region after GEMM2; redp (16KB) overlays base after CsF reads.
// Stats atomics XCD-classed: out_sum/out_sq are [8][128]; class = blockIdx&7.
__global__ __launch_bounds__(512) void mlp_mfma(
    const unsigned short* __restrict__ A,      // [M][128] f16
    const unsigned short* __restrict__ Wta,    // [128][128] f16 N-major
    const float* __restrict__ biasa,
    const unsigned short* __restrict__ Wtb,
    const float* __restrict__ biasb,
    unsigned short* __restrict__ Cb,           // optional f16 out
    float* __restrict__ Cf,                    // optional fp32 out
    float* __restrict__ out_sum, float* __restrict__ out_sq)
{
    __shared__ float4 smem4[69632 / 16];
    char* smem = (char*)smem4;
    _Float16 (*Wsa)[136]  = (_Float16(*)[136])smem;            // 128x136 f16
    _Float16 (*Wsb)[136]  = (_Float16(*)[136])(smem + 34816);  // 128x136 f16
    _Float16 (*Cs16)[136] = (_Float16(*)[136])smem;            // overlays Wsa
    float (*CsF)[132]     = (float(*)[132])smem;               // 128x132 f32 = 67584
    float* redp           = (float*)smem;                      // 2*16*128 f32 = 16KB

    const int t = threadIdx.x;
    const int wave = t >> 6, lane = t & 63;
    const int m16 = lane & 15, quad = lane >> 4;
    const int row0 = blockIdx.x * 128;
    const int arow = row0 + wave * 16 + m16;

    #pragma unroll
    for (int i = 0; i < 4; ++i) {
        int idx = t + i * 512;
        int r = idx >> 4, s = idx & 15;
        *(float4*)&Wsa[r][s * 8] = ((const float4*)Wta)[idx];
        *(float4*)&Wsb[r][s * 8] = ((const float4*)Wtb)[idx];
    }

    f16x8 afrag[4];
    if (arow < NNODES) {
        const _Float16* ar = (const _Float16*)A + (long)arow * HD + quad * 8;
        #pragma unroll
        for (int kc = 0; kc < 4; ++kc)
            afrag[kc] = *(const f16x8*)(ar + kc * 32);
    } else {
        #pragma unroll
        for (int kc = 0; kc < 4; ++kc)
            afrag[kc] = f16x8{0, 0, 0, 0, 0, 0, 0, 0};
    }
    __syncthreads();

    // ---- GEMM 1 (reads Wsa)
    f32x4 accs[8];
    #pragma unroll
    for (int np = 0; np < 8; np += 2) {
        f32x4 a0 = {0.f, 0.f, 0.f, 0.f};
        f32x4 a1 = {0.f, 0.f, 0.f, 0.f};
        const _Float16* b0 = &Wsa[np * 16 + m16][quad * 8];
        const _Float16* b1 = &Wsa[(np + 1) * 16 + m16][quad * 8];
        #pragma unroll
        for (int kc = 0; kc < 4; ++kc) {
            f16x8 f0 = *(const f16x8*)(b0 + kc * 32);
            f16x8 f1 = *(const f16x8*)(b1 + kc * 32);
            a0 = __builtin_amdgcn_mfma_f32_16x16x32_f16(afrag[kc], f0, a0, 0, 0, 0);
            a1 = __builtin_amdgcn_mfma_f32_16x16x32_f16(afrag[kc], f1, a1, 0, 0, 0);
        }
        accs[np] = a0; accs[np + 1] = a1;
    }
    __syncthreads();                       // all Wsa reads done

    // bias+ReLU -> f16 into Cs16 (overlays Wsa); rows disjoint per wave
    #pragma unroll
    for (int np = 0; np < 8; ++np) {
        int c = np * 16 + m16;
        float bb = biasa[c];
        #pragma unroll
        for (int r = 0; r < 4; ++r)
            Cs16[wave * 16 + quad * 4 + r][c] =
                (_Float16)fmaxf(accs[np][r] + bb, 0.f);
    }
    __syncthreads();                       // Cs16 complete

    // ---- GEMM 2 (A2 from Cs16, weights Wsb)
    f16x8 afrag2[4];
    {
        const int crow = wave * 16 + m16;
        #pragma unroll
        for (int kc = 0; kc < 4; ++kc)
            afrag2[kc] = *(const f16x8*)&Cs16[crow][quad * 8 + kc * 32];
    }
    #pragma unroll
    for (int np = 0; np < 8; np += 2) {
        f32x4 a0 = {0.f, 0.f, 0.f, 0.f};
        f32x4 a1 = {0.f, 0.f, 0.f, 0.f};
        const _Float16* b0 = &Wsb[np * 16 + m16][quad * 8];
        const _Float16* b1 = &Wsb[(np + 1) * 16 + m16][quad * 8];
        #pragma unroll
        for (int kc = 0; kc < 4; ++kc) {
            f16x8 f0 = *(const f16x8*)(b0 + kc * 32);
            f16x8 f1 = *(const f16x8*)(b1 + kc * 32);
            a0 = __builtin_amdgcn_mfma_f32_16x16x32_f16(afrag2[kc], f0, a0, 0, 0, 0);
            a1 = __builtin_amdgcn_mfma_f32_16x16x32_f16(afrag2[kc], f1, a1, 0, 0, 0);
        }
        accs[np] = a0; accs[np + 1] = a1;
    }
    __syncthreads();                       // all Cs16/Wsb reads done

    // epilogue fp32 C over whole region
    #pragma unroll
    for (int np = 0; np < 8; ++np) {
        int c = np * 16 + m16;
        float bb = biasb[c];
        #pragma unroll
        for (int r = 0; r < 4; ++r)
            CsF[wave * 16 + quad * 4 + r][c] = accs[np][r] + bb;
    }
    __syncthreads();                       // CsF complete

    const int s4 = t & 31;                 // float4 col
    const int rb = t >> 5;                 // 16 row groups
    float lsum[4] = {}, lsq[4] = {};
    #pragma unroll
    for (int i = 0; i < 8; ++i) {
        int r = rb + i * 16;
        int row = row0 + r;
        float4 v = *(const float4*)&CsF[r][s4 * 4];
        if (row < NNODES) {
            if (Cb) {
                ushort4 o;
                o.x = f2h_bits(v.x); o.y = f2h_bits(v.y);
                o.z = f2h_bits(v.z); o.w = f2h_bits(v.w);
                ((ushort4*)Cb)[(long)row * 32 + s4] = o;
            }
            if (Cf) ((float4*)Cf)[(long)row * 32 + s4] = v;
            lsum[0] += v.x; lsum[1] += v.y; lsum[2] += v.z; lsum[3] += v.w;
            lsq[0] = fmaf(v.x, v.x, lsq[0]);
            lsq[1] = fmaf(v.y, v.y, lsq[1]);
            lsq[2] = fmaf(v.z, v.z, lsq[2]);
            lsq[3] = fmaf(v.w, v.w, lsq[3]);
        }
    }
    __syncthreads();                       // CsF reads done before redp overlay

    #pragma unroll
    for (int j = 0; j < 4; ++j) {
        redp[(0 * 16 + rb) * 128 + s4 * 4 + j] = lsum[j];
        redp[(1 * 16 + rb) * 128 + s4 * 4 + j] = lsq[j];
    }
    __syncthreads();
    if (t < 128) {
        float s = 0.f, q = 0.f;
        #pragma unroll
        for (int g = 0; g < 16; ++g) {
            s += redp[g * 128 + t];
            q += redp[(16 + g) * 128 + t];
        }
        const int cls = blockIdx.x & 7;            // XCD-classed stats region
        atomicAdd(&out_sum[cls * 128 + t], s);
        atomicAdd(&out_sq[cls * 128 + t],  q);
    }
}

// ================= BN fold (sums the 8 class copies) =================
__global__ void bn_prep(const float* __restrict__ ssum, const float* __restrict__ ssq,
                        const float* __restrict__ gamma, const float* __restrict__ beta,
                        float* __restrict__ scale, float* __restrict__ shift)
{
    int c = threadIdx.x;
    float s = 0.f, q = 0.f;
    #pragma unroll
    for (int g = 0; g < 8; ++g) {
        s += ssum[g * 128 + c];
        q += ssq[g * 128 + c];
    }
    const float invN = 1.0f / (float)NNODES;
    float m = s * invN;
    float var = fmaf(-m, m, q * invN);
    float rs = rsqrtf(var + 1e-5f);
    float sc = gamma[c] * rs;
    scale[c] = sc;
    shift[c] = beta[c] - m * sc;
}

// ========== projection + softmax, BN2+ReLU fused on load ==========
__global__ __launch_bounds__(256) void out_proj_softmax(
    const float* __restrict__ H, const float* __restrict__ Wout,
    const float* __restrict__ scale, const float* __restrict__ shift,
    const float* __restrict__ log_tau,
    float* __restrict__ outS, float* __restrict__ outL)
{
    __shared__ float As[HD][20];
    const int t = threadIdx.x;
    const long row0 = (long)blockIdx.x * 16;

    #pragma unroll
    for (int i = 0; i < 8; ++i) {
        int idx = t + i * 256;
        int r = idx >> 7, cc = idx & 127;
        float v = H[(row0 + r) * HD + cc];
        As[cc][r] = fmaxf(fmaf(v, scale[cc], shift[cc]), 0.f);
    }
    __syncthreads();

    const int c = t & 63;
    const int g = t >> 6;
    float acc[4] = {};

    float wq[8];
    #pragma unroll
    for (int i = 0; i < 8; ++i) wq[i] = Wout[i * KOUT + c];

    #pragma unroll 1
    for (int kc = 0; kc < HD; kc += 8) {
        float wn[8];
        if (kc + 8 < HD) {
            #pragma unroll
            for (int i = 0; i < 8; ++i) wn[i] = Wout[(kc + 8 + i) * KOUT + c];
        }
        #pragma unroll
        for (int i = 0; i < 8; ++i) {
            float4 a = *(const float4*)&As[kc + i][g * 4];
            acc[0] = fmaf(a.x, wq[i], acc[0]);
            acc[1] = fmaf(a.y, wq[i], acc[1]);
            acc[2] = fmaf(a.z, wq[i], acc[2]);
            acc[3] = fmaf(a.w, wq[i], acc[3]);
        }
        if (kc + 8 < HD) {
            #pragma unroll
            for (int i = 0; i < 8; ++i) wq[i] = wn[i];
        }
    }

    float inv_tau = __expf(-log_tau[0]);
    #pragma unroll
    for (int i = 0; i < 4; ++i) {
        float z = acc[i] * inv_tau;
        float m = z;
        #pragma unroll
        for (int o = 32; o > 0; o >>= 1) m = fmaxf(m, __shfl_xor(m, o));
        float e = __expf(z - m);
        float s = e;
        #pragma unroll
        for (int o = 32; o > 0; o >>= 1) s += __shfl_xor(s, o);
        long oi = (row0 + g * 4 + i) * KOUT + c;
        outS[oi] = e / s;
        outL[oi] = acc[i];
    }
}

extern "C" void kernel_launch(void* const* d_in, const int* in_sizes, int n_in,
                              void* d_out, int out_size, void* d_ws, size_t ws_size,
                              hipStream_t stream)
{
    const float* x      = (const float*)d_in[0];
    const int*   ei     = (const int*)d_in[1];
    const float* W1a    = (const float*)d_in[2];
    const float* b1a    = (const float*)d_in[3];
    const float* W1b    = (const float*)d_in[4];
    const float* b1b    = (const float*)d_in[5];
    const float* eps1   = (const float*)d_in[6];
    const float* gamma1 = (const float*)d_in[7];
    const float* beta1  = (const float*)d_in[8];
    const float* W2a    = (const float*)d_in[9];
    const float* b2a    = (const float*)d_in[10];
    const float* W2b    = (const float*)d_in[11];
    const float* b2b    = (const float*)d_in[12];
    const float* eps2   = (const float*)d_in[13];
    const float* gamma2 = (const float*)d_in[14];
    const float* beta2  = (const float*)d_in[15];
    const float* Wout   = (const float*)d_in[16];
    const float* ltau   = (const float*)d_in[17];

    const size_t NB = (size_t)NNODES * HD;
    float* B0 = (float*)d_ws;
    float* B1 = B0 + NB;
    float* B2 = B1 + NB;
    float* ST = B2 + NB;             // stats: 4 x [8][128] classed + scales
    float* sum1 = ST, *sq1 = ST + 1024, *sum2 = ST + 2048, *sq2 = ST + 3072;
    float* scale1 = ST + 4096, *shift1 = ST + 4224;
    float* scale2 = ST + 4352, *shift2 = ST + 4480;

    unsigned short* xh  = (unsigned short*)B2;   // f16 x (CSR + gather1)
    unsigned short* h0h = (unsigned short*)B0;   // gather1 out; mlp1 in-place -> hh
    unsigned short* hh  = (unsigned short*)B0;   // h1 f16
    unsigned short* h2h = (unsigned short*)B2;   // gather2 out

    int* I0        = (int*)(ST + 4608);
    int* deg       = I0;
    int* incl      = I0 + NODE_PAD;
    int* row_start = I0 + 2 * NODE_PAD;
    int* row_end   = I0 + 3 * NODE_PAD;
    int* bsum      = I0 + 4 * NODE_PAD;
    int* col       = bsum + 256;                // NEDGES ints
    int* cnt       = col + NEDGES;              // [64][NODE_PAD] ints = 12.8MB
    unsigned short* wt1a = (unsigned short*)(cnt + NCHUNK * NODE_PAD);
    unsigned short* wt1b = wt1a + HD * HD;
    unsigned short* wt2a = wt1b + HD * HD;
    unsigned short* wt2b = wt2a + HD * HD;

    const int SCAN_BLKS = (NNODES + 255) / 256;   // 196
    const int GEMM_BLKS = (NNODES + 127) / 128;   // 391 (M=128 tile)
    const int GATH_BLKS = (NNODES + 31) / 32;     // 1563 (32 nodes/block)

    hipMemsetAsync(ST, 0, 4096 * sizeof(float), stream);
    prep_all<<<HIST_BLKS + 6506, 256, 0, stream>>>(x, xh, W1a, W1b, W2a, W2b,
                                                   wt1a, wt1b, wt2a, wt2b, ei, cnt);
    cscan<<<SCAN_BLKS, 256, 0, stream>>>(cnt, deg);
    scan_a<<<SCAN_BLKS, 256, 0, stream>>>(deg, incl, bsum);
    scan_c<<<SCAN_BLKS, 256, 0, stream>>>(deg, incl, bsum, row_start, row_end);
    edge_fill<<<HIST_BLKS, 256, 0, stream>>>(ei, row_start, cnt, col);

    // ---- layer 1
    gin_gather_w<false><<<GATH_BLKS, 256, 0, stream>>>(
        xh, col, row_start, row_end, eps1, nullptr, nullptr, h0h);
    mlp_mfma<<<GEMM_BLKS, 512, 0, stream>>>(
        h0h, wt1a, b1a, wt1b, b1b, hh, nullptr, sum1, sq1);
    bn_prep<<<1, 128, 0, stream>>>(sum1, sq1, gamma1, beta1, scale1, shift1);

    // ---- layer 2 (BN1+ReLU fused into gather reads)
    gin_gather_w<true><<<GATH_BLKS, 256, 0, stream>>>(
        hh, col, row_start, row_end, eps2, scale1, shift1, h2h);
    mlp_mfma<<<GEMM_BLKS, 512, 0, stream>>>(
        h2h, wt2a, b2a, wt2b, b2b, nullptr, B1, sum2, sq2);
    bn_prep<<<1, 128, 0, stream>>>(sum2, sq2, gamma2, beta2, scale2, shift2);

    // ---- projection + softmax (BN2+ReLU fused on load)
    out_proj_softmax<<<NNODES / 16, 256, 0, stream>>>(
        B1, Wout, scale2, shift2, ltau,
        (float*)d_out, (float*)d_out + (size_t)NNODES * KOUT);
}

// Round 16
// 267.458 us; speedup vs baseline: 1.1572x; 1.0170x over previous
//
#include <hip/hip_runtime.h>
#include <hip/hip_fp16.h>

// GIN 2-layer + BN + softmax pipeline for MI355X. All tensors fp32; edges int32.
// R27: cscan folded into scan_a (each thread runs its node's 64-chunk prefix
// in-place -> deg in-register -> block scan). -1 dispatch, -1 deg roundtrip.
// KEEP: R26 structure (best 272.0us) -- atomic-free counting-sort edge_fill
// (LDS-rank + per-chunk bases), f16 pipeline, M=128 mlp, XCD-classed stats.
//
// Workspace timeline (B0/B1/B2 = 25.6 MB fp32 regions; h* = f16 aliases):
//   prep_all: chunk-hists->cnt ; xh=(u16*)B2 <- x ; wt* <- W*
//   scan_a:   cnt prefix (per node) -> bases + deg + block-incl
//   gather1:  reads xh(B2)    -> h0h=(u16*)B0
//   mlp1:     A=h0h(B0)       -> hh=(u16*)B0 IN-PLACE + stats1 (8-class)
//   gather2:  reads hh(B0)+BN -> h2h=(u16*)B2 (kills xh, OK)
//   mlp2:     A=h2h(B2)       -> h2 fp32 = B1 + stats2 (8-class)
//   out_proj: reads B1 (+BN2 fused)

#define NNODES 50000
#define NEDGES 800000
#define HD 128
#define KOUT 64
#define NCLS 8
#define CLSW 6250            // nodes per class window (NNODES/NCLS)
#define HIST_BLKS 512        // 64 edge-chunks x 8 classes
#define NCHUNK 64
#define CH_E 12500           // edges per chunk
#define NODE_PAD 50048       // padded node stride for cnt rows

typedef __attribute__((ext_vector_type(8))) _Float16 f16x8;
typedef __attribute__((ext_vector_type(4))) float f32x4;

__device__ __forceinline__ unsigned short f2h_bits(float f) {   // RNE f32->f16
    _Float16 h = (_Float16)f;
    return __builtin_bit_cast(unsigned short, h);
}
__device__ __forceinline__ f16x8 h8_relu(f16x8 v) {
    #pragma unroll
    for (int i = 0; i < 8; ++i) v[i] = (v[i] > (_Float16)0.f) ? v[i] : (_Float16)0.f;
    return v;
}

// ===== prep: per-chunk classed hist -> cnt | x -> f16 | weight transposes =====
__global__ __launch_bounds__(256) void prep_all(
    const float* __restrict__ x, unsigned short* __restrict__ xh,
    const float* __restrict__ W1a, const float* __restrict__ W1b,
    const float* __restrict__ W2a, const float* __restrict__ W2b,
    unsigned short* __restrict__ wt1a, unsigned short* __restrict__ wt1b,
    unsigned short* __restrict__ wt2a, unsigned short* __restrict__ wt2b,
    const int* __restrict__ ei, int* __restrict__ cnt)
{
    __shared__ int h[CLSW];                 // 25000 B (hist blocks only)
    int bid = blockIdx.x;
    if (bid < HIST_BLKS) {                  // classed LDS histogram, int4 dst
        const int cls = bid & 7;
        const int chunk = bid >> 3;
        const int lo = cls * CLSW;
        const int e0 = chunk * CH_E;
        for (int i = threadIdx.x; i < CLSW; i += 256) h[i] = 0;
        __syncthreads();
        const int4* d4p = (const int4*)(ei + NEDGES) + (e0 >> 2);   // 3125 int4
        for (int i = threadIdx.x; i < CH_E / 4; i += 256) {
            int4 d = d4p[i];
            unsigned a0 = (unsigned)(d.x - lo), a1 = (unsigned)(d.y - lo);
            unsigned a2 = (unsigned)(d.z - lo), a3 = (unsigned)(d.w - lo);
            if (a0 < (unsigned)CLSW) atomicAdd(&h[a0], 1);
            if (a1 < (unsigned)CLSW) atomicAdd(&h[a1], 1);
            if (a2 < (unsigned)CLSW) atomicAdd(&h[a2], 1);
            if (a3 < (unsigned)CLSW) atomicAdd(&h[a3], 1);
        }
        __syncthreads();
        int* crow = cnt + chunk * NODE_PAD + lo;
        for (int i = threadIdx.x; i < CLSW; i += 256)
            crow[i] = h[i];                 // plain store; window owned by block
    } else if (bid < HIST_BLKS + 6250) {    // x -> f16 (float4 per thread)
        int i = (bid - HIST_BLKS) * 256 + threadIdx.x;
        float4 v = ((const float4*)x)[i];
        ushort4 o;
        o.x = f2h_bits(v.x); o.y = f2h_bits(v.y);
        o.z = f2h_bits(v.z); o.w = f2h_bits(v.w);
        ((ushort4*)xh)[i] = o;
    } else {                                // Wt[n][k] = f16(W[k][n])
        int wb = bid - (HIST_BLKS + 6250);  // 0..255
        int w = wb >> 6;
        int idx = (wb & 63) * 256 + threadIdx.x;   // 0..16383
        int n = idx >> 7, k = idx & 127;
        const float* W = (w == 0) ? W1a : (w == 1) ? W1b : (w == 2) ? W2a : W2b;
        unsigned short* Wt = (w == 0) ? wt1a : (w == 1) ? wt1b : (w == 2) ? wt2a : wt2b;
        Wt[idx] = f2h_bits(W[k * HD + n]);
    }
}

// ===== scan_a: per-node chunk prefix (cscan folded) + deg + block-incl =====
__global__ __launch_bounds__(256) void scan_a(
    int* __restrict__ cnt, int* __restrict__ deg,
    int* __restrict__ incl, int* __restrict__ bsum)
{
    __shared__ int s[256];
    int t = threadIdx.x, idx = blockIdx.x * 256 + t;
    int run = 0;
    if (idx < NNODES) {
        int* p = cnt + idx;
        #pragma unroll 8
        for (int c = 0; c < NCHUNK; ++c) {
            int v = p[(long)c * NODE_PAD];
            p[(long)c * NODE_PAD] = run;
            run += v;
        }
        deg[idx] = run;
    }
    s[t] = run; __syncthreads();
    #pragma unroll
    for (int off = 1; off < 256; off <<= 1) {
        int tmp = (t >= off) ? s[t - off] : 0;
        __syncthreads();
        s[t] += tmp;
        __syncthreads();
    }
    if (idx < NNODES) incl[idx] = s[t];
    if (t == 255) bsum[blockIdx.x] = s[255];
}

// scan_c: row_start + row_end (scan_b folded; no cur/atomics)
__global__ __launch_bounds__(256) void scan_c(
    const int* __restrict__ deg, const int* __restrict__ incl,
    const int* __restrict__ bsum,
    int* __restrict__ row_start, int* __restrict__ row_end)
{
    __shared__ int s[256];
    int b = blockIdx.x, t = threadIdx.x;
    int p = 0;
    for (int i = t; i < b; i += 256) p += bsum[i];
    s[t] = p; __syncthreads();
    #pragma unroll
    for (int off = 128; off > 0; off >>= 1) {
        if (t < off) s[t] += s[t + off];
        __syncthreads();
    }
    int off0 = s[0];
    int idx = b * 256 + t;
    if (idx >= NNODES) return;
    int inc = incl[idx];
    row_start[idx] = inc - deg[idx] + off0;
    row_end[idx] = inc + off0;
}

// XCD-partitioned fill, ATOMIC-FREE: 64 chunks x 8 classes. slot = rs[d] +
// cnt[chunk][d] (earlier-chunk base) + LDS rank within (chunk, class window).
__global__ __launch_bounds__(256) void edge_fill(
    const int* __restrict__ ei, const int* __restrict__ rs,
    const int* __restrict__ cnt, int* __restrict__ col)
{
    __shared__ int h[CLSW];
    const int cls = blockIdx.x & 7;
    const int chunk = blockIdx.x >> 3;
    const int lo = cls * CLSW;
    const int e0 = chunk * CH_E;
    const int* cb = cnt + chunk * NODE_PAD;
    for (int i = threadIdx.x; i < CLSW; i += 256) h[i] = 0;
    __syncthreads();
    const int4* d4p = (const int4*)(ei + NEDGES) + (e0 >> 2);
    const int4* s4p = (const int4*)ei + (e0 >> 2);
    for (int i = threadIdx.x; i < CH_E / 4; i += 256) {
        int4 d = d4p[i];
        int4 s = s4p[i];
        unsigned a0 = (unsigned)(d.x - lo), a1 = (unsigned)(d.y - lo);
        unsigned a2 = (unsigned)(d.z - lo), a3 = (unsigned)(d.w - lo);
        if (a0 < (unsigned)CLSW) {
            int r = atomicAdd(&h[a0], 1);
            col[rs[d.x] + cb[d.x] + r] = s.x;
        }
        if (a1 < (unsigned)CLSW) {
            int r = atomicAdd(&h[a1], 1);
            col[rs[d.y] + cb[d.y] + r] = s.y;
        }
        if (a2 < (unsigned)CLSW) {
            int r = atomicAdd(&h[a2], 1);
            col[rs[d.z] + cb[d.z] + r] = s.z;
        }
        if (a3 < (unsigned)CLSW) {
            int r = atomicAdd(&h[a3], 1);
            col[rs[d.w] + cb[d.w] + r] = s.w;
        }
    }
}

// ========== gather (f16 in/out), 16 lanes/node x 16B loads, pk-f16 math ==========
// 2 serial nodes/group (32 nodes/block, grid 1563 = full TLP) + 8-deep load
// unroll (ILP for the L3-latency-bound random reads).
template<bool BN>
__global__ __launch_bounds__(256) void gin_gather_w(
    const unsigned short* __restrict__ Xh, const int* __restrict__ col,
    const int* __restrict__ rs, const int* __restrict__ re,
    const float* __restrict__ eps,
    const float* __restrict__ scale, const float* __restrict__ shift,
    unsigned short* __restrict__ H0h)
{
    const int t = threadIdx.x;
    const int g = t >> 4;            // 16 groups
    const int lane = t & 15;         // 16B per lane -> 8 feats
    const f16x8* X8 = (const f16x8*)Xh;        // 16 f16x8 per row
    const float alphaf = 1.f + eps[0];

    f16x8 sc8, sh8, al8;
    #pragma unroll
    for (int i = 0; i < 8; ++i) al8[i] = (_Float16)alphaf;
    if (BN) {
        #pragma unroll
        for (int i = 0; i < 8; ++i) {
            sc8[i] = (_Float16)scale[lane * 8 + i];
            sh8[i] = (_Float16)shift[lane * 8 + i];
        }
    }

    #pragma unroll 1
    for (int nn = 0; nn < 2; ++nn) {
        int node = blockIdx.x * 32 + nn * 16 + g;
        if (node >= NNODES) continue;

        f16x8 acc = X8[(long)node * 16 + lane];
        if (BN) acc = h8_relu(acc * sc8 + sh8);
        acc = acc * al8;

        int j = rs[node], end = re[node];
        for (; j + 7 < end; j += 8) {
            int c0 = col[j],     c1 = col[j + 1], c2 = col[j + 2], c3 = col[j + 3];
            int c4 = col[j + 4], c5 = col[j + 5], c6 = col[j + 6], c7 = col[j + 7];
            f16x8 u0 = X8[(long)c0 * 16 + lane];
            f16x8 u1 = X8[(long)c1 * 16 + lane];
            f16x8 u2 = X8[(long)c2 * 16 + lane];
            f16x8 u3 = X8[(long)c3 * 16 + lane];
            f16x8 u4 = X8[(long)c4 * 16 + lane];
            f16x8 u5 = X8[(long)c5 * 16 + lane];
            f16x8 u6 = X8[(long)c6 * 16 + lane];
            f16x8 u7 = X8[(long)c7 * 16 + lane];
            if (BN) {
                u0 = h8_relu(u0 * sc8 + sh8); u1 = h8_relu(u1 * sc8 + sh8);
                u2 = h8_relu(u2 * sc8 + sh8); u3 = h8_relu(u3 * sc8 + sh8);
                u4 = h8_relu(u4 * sc8 + sh8); u5 = h8_relu(u5 * sc8 + sh8);
                u6 = h8_relu(u6 * sc8 + sh8); u7 = h8_relu(u7 * sc8 + sh8);
            }
            acc += ((u0 + u1) + (u2 + u3)) + ((u4 + u5) + (u6 + u7));
        }
        for (; j + 3 < end; j += 4) {
            f16x8 u0 = X8[(long)col[j]     * 16 + lane];
            f16x8 u1 = X8[(long)col[j + 1] * 16 + lane];
            f16x8 u2 = X8[(long)col[j + 2] * 16 + lane];
            f16x8 u3 = X8[(long)col[j + 3] * 16 + lane];
            if (BN) {
                u0 = h8_relu(u0 * sc8 + sh8); u1 = h8_relu(u1 * sc8 + sh8);
                u2 = h8_relu(u2 * sc8 + sh8); u3 = h8_relu(u3 * sc8 + sh8);
            }
            acc += (u0 + u1) + (u2 + u3);
        }
        for (; j < end; ++j) {
            f16x8 u = X8[(long)col[j] * 16 + lane];
            if (BN) u = h8_relu(u * sc8 + sh8);
            acc += u;
        }

        ((f16x8*)H0h)[(long)node * 16 + lane] = acc;
    }
}

// ========== fused MLP: C = (ReLU(A@Wa + ba))@Wb + bb, + per-col stats ==========
// M=128 tile, 512 threads (8 waves). LDS: Wsa(34816)+Wsb(34816)=69632 B.
// Cs16 f16[128][136] overlays Wsa after GEMM1; CsF fp32[128][132] overlays the
// whole region after GEMM2; redp (16KB) overlays base after CsF reads.
// Stats atomics XCD-classed: out_sum/out_sq are [8][128]; class = blockIdx&7.
__global__ __launch_bounds__(512) void mlp_mfma(
    const unsigned short* __restrict__ A,      // [M][128] f16
    const unsigned short* __restrict__ Wta,    // [128][128] f16 N-major
    const float* __restrict__ biasa,
    const unsigned short* __restrict__ Wtb,
    const float* __restrict__ biasb,
    unsigned short* __restrict__ Cb,           // optional f16 out
    float* __restrict__ Cf,                    // optional fp32 out
    float* __restrict__ out_sum, float* __restrict__ out_sq)
{
    __shared__ float4 smem4[69632 / 16];
    char* smem = (char*)smem4;
    _Float16 (*Wsa)[136]  = (_Float16(*)[136])smem;            // 128x136 f16
    _Float16 (*Wsb)[136]  = (_Float16(*)[136])(smem + 34816);  // 128x136 f16
    _Float16 (*Cs16)[136] = (_Float16(*)[136])smem;            // overlays Wsa
    float (*CsF)[132]     = (float(*)[132])smem;               // 128x132 f32 = 67584
    float* redp           = (float*)smem;                      // 2*16*128 f32 = 16KB

    const int t = threadIdx.x;
    const int wave = t >> 6, lane = t & 63;
    const int m16 = lane & 15, quad = lane >> 4;
    const int row0 = blockIdx.x * 128;
    const int arow = row0 + wave * 16 + m16;

    #pragma unroll
    for (int i = 0; i < 4; ++i) {
        int idx = t + i * 512;
        int r = idx >> 4, s = idx & 15;
        *(float4*)&Wsa[r][s * 8] = ((const float4*)Wta)[idx];
        *(float4*)&Wsb[r][s * 8] = ((const float4*)Wtb)[idx];
    }

    f16x8 afrag[4];
    if (arow < NNODES) {
        const _Float16* ar = (const _Float16*)A + (long)arow * HD + quad * 8;
        #pragma unroll
        for (int kc = 0; kc < 4; ++kc)
            afrag[kc] = *(const f16x8*)(ar + kc * 32);
    } else {
        #pragma unroll
        for (int kc = 0; kc < 4; ++kc)
            afrag[kc] = f16x8{0, 0, 0, 0, 0, 0, 0, 0};
    }
    __syncthreads();

    // ---- GEMM 1 (reads Wsa)
    f32x4 accs[8];
    #pragma unroll
    for (int np = 0; np < 8; np += 2) {
        f32x4 a0 = {0.f, 0.f, 0.f, 0.f};
        f32x4 a1 = {0.f, 0.f, 0.f, 0.f};
        const _Float16* b0 = &Wsa[np * 16 + m16][quad * 8];
        const _Float16* b1 = &Wsa[(np + 1) * 16 + m16][quad * 8];
        #pragma unroll
        for (int kc = 0; kc < 4; ++kc) {
            f16x8 f0 = *(const f16x8*)(b0 + kc * 32);
            f16x8 f1 = *(const f16x8*)(b1 + kc * 32);
            a0 = __builtin_amdgcn_mfma_f32_16x16x32_f16(afrag[kc], f0, a0, 0, 0, 0);
            a1 = __builtin_amdgcn_mfma_f32_16x16x32_f16(afrag[kc], f1, a1, 0, 0, 0);
        }
        accs[np] = a0; accs[np + 1] = a1;
    }
    __syncthreads();                       // all Wsa reads done

    // bias+ReLU -> f16 into Cs16 (overlays Wsa); rows disjoint per wave
    #pragma unroll
    for (int np = 0; np < 8; ++np) {
        int c = np * 16 + m16;
        float bb = biasa[c];
        #pragma unroll
        for (int r = 0; r < 4; ++r)
            Cs16[wave * 16 + quad * 4 + r][c] =
                (_Float16)fmaxf(accs[np][r] + bb, 0.f);
    }
    __syncthreads();                       // Cs16 complete

    // ---- GEMM 2 (A2 from Cs16, weights Wsb)
    f16x8 afrag2[4];
    {
        const int crow = wave * 16 + m16;
        #pragma unroll
        for (int kc = 0; kc < 4; ++kc)
            afrag2[kc] = *(const f16x8*)&Cs16[crow][quad * 8 + kc * 32];
    }
    #pragma unroll
    for (int np = 0; np < 8; np += 2) {
        f32x4 a0 = {0.f, 0.f, 0.f, 0.f};
        f32x4 a1 = {0.f, 0.f, 0.f, 0.f};
        const _Float16* b0 = &Wsb[np * 16 + m16][quad * 8];
        const _Float16* b1 = &Wsb[(np + 1) * 16 + m16][quad * 8];
        #pragma unroll
        for (int kc = 0; kc < 4; ++kc) {
            f16x8 f0 = *(const f16x8*)(b0 + kc * 32);
            f16x8 f1 = *(const f16x8*)(b1 + kc * 32);
            a0 = __builtin_amdgcn_mfma_f32_16x16x32_f16(afrag2[kc], f0, a0, 0, 0, 0);
            a1 = __builtin_amdgcn_mfma_f32_16x16x32_f16(afrag2[kc], f1, a1, 0, 0, 0);
        }
        accs[np] = a0; accs[np + 1] = a1;
    }
    __syncthreads();                       // all Cs16/Wsb reads done

    // epilogue fp32 C over whole region
    #pragma unroll
    for (int np = 0; np < 8; ++np) {
        int c = np * 16 + m16;
        float bb = biasb[c];
        #pragma unroll
        for (int r = 0; r < 4; ++r)
            CsF[wave * 16 + quad * 4 + r][c] = accs[np][r] + bb;
    }
    __syncthreads();                       // CsF complete

    const int s4 = t & 31;                 // float4 col
    const int rb = t >> 5;                 // 16 row groups
    float lsum[4] = {}, lsq[4] = {};
    #pragma unroll
    for (int i = 0; i < 8; ++i) {
        int r = rb + i * 16;
        int row = row0 + r;
        float4 v = *(const float4*)&CsF[r][s4 * 4];
        if (row < NNODES) {
            if (Cb) {
                ushort4 o;
                o.x = f2h_bits(v.x); o.y = f2h_bits(v.y);
                o.z = f2h_bits(v.z); o.w = f2h_bits(v.w);
                ((ushort4*)Cb)[(long)row * 32 + s4] = o;
            }
            if (Cf) ((float4*)Cf)[(long)row * 32 + s4] = v;
            lsum[0] += v.x; lsum[1] += v.y; lsum[2] += v.z; lsum[3] += v.w;
            lsq[0] = fmaf(v.x, v.x, lsq[0]);
            lsq[1] = fmaf(v.y, v.y, lsq[1]);
            lsq[2] = fmaf(v.z, v.z, lsq[2]);
            lsq[3] = fmaf(v.w, v.w, lsq[3]);
        }
    }
    __syncthreads();                       // CsF reads done before redp overlay

    #pragma unroll
    for (int j = 0; j < 4; ++j) {
        redp[(0 * 16 + rb) * 128 + s4 * 4 + j] = lsum[j];
        redp[(1 * 16 + rb) * 128 + s4 * 4 + j] = lsq[j];
    }
    __syncthreads();
    if (t < 128) {
        float s = 0.f, q = 0.f;
        #pragma unroll
        for (int g = 0; g < 16; ++g) {
            s += redp[g * 128 + t];
            q += redp[(16 + g) * 128 + t];
        }
        const int cls = blockIdx.x & 7;            // XCD-classed stats region
        atomicAdd(&out_sum[cls * 128 + t], s);
        atomicAdd(&out_sq[cls * 128 + t],  q);
    }
}

// ================= BN fold (sums the 8 class copies) =================
__global__ void bn_prep(const float* __restrict__ ssum, const float* __restrict__ ssq,
                        const float* __restrict__ gamma, const float* __restrict__ beta,
                        float* __restrict__ scale, float* __restrict__ shift)
{
    int c = threadIdx.x;
    float s = 0.f, q = 0.f;
    #pragma unroll
    for (int g = 0; g < 8; ++g) {
        s += ssum[g * 128 + c];
        q += ssq[g * 128 + c];
    }
    const float invN = 1.0f / (float)NNODES;
    float m = s * invN;
    float var = fmaf(-m, m, q * invN);
    float rs = rsqrtf(var + 1e-5f);
    float sc = gamma[c] * rs;
    scale[c] = sc;
    shift[c] = beta[c] - m * sc;
}

// ========== projection + softmax, BN2+ReLU fused on load ==========
__global__ __launch_bounds__(256) void out_proj_softmax(
    const float* __restrict__ H, const float* __restrict__ Wout,
    const float* __restrict__ scale, const float* __restrict__ shift,
    const float* __restrict__ log_tau,
    float* __restrict__ outS, float* __restrict__ outL)
{
    __shared__ float As[HD][20];
    const int t = threadIdx.x;
    const long row0 = (long)blockIdx.x * 16;

    #pragma unroll
    for (int i = 0; i < 8; ++i) {
        int idx = t + i * 256;
        int r = idx >> 7, cc = idx & 127;
        float v = H[(row0 + r) * HD + cc];
        As[cc][r] = fmaxf(fmaf(v, scale[cc], shift[cc]), 0.f);
    }
    __syncthreads();

    const int c = t & 63;
    const int g = t >> 6;
    float acc[4] = {};

    float wq[8];
    #pragma unroll
    for (int i = 0; i < 8; ++i) wq[i] = Wout[i * KOUT + c];

    #pragma unroll 1
    for (int kc = 0; kc < HD; kc += 8) {
        float wn[8];
        if (kc + 8 < HD) {
            #pragma unroll
            for (int i = 0; i < 8; ++i) wn[i] = Wout[(kc + 8 + i) * KOUT + c];
        }
        #pragma unroll
        for (int i = 0; i < 8; ++i) {
            float4 a = *(const float4*)&As[kc + i][g * 4];
            acc[0] = fmaf(a.x, wq[i], acc[0]);
            acc[1] = fmaf(a.y, wq[i], acc[1]);
            acc[2] = fmaf(a.z, wq[i], acc[2]);
            acc[3] = fmaf(a.w, wq[i], acc[3]);
        }
        if (kc + 8 < HD) {
            #pragma unroll
            for (int i = 0; i < 8; ++i) wq[i] = wn[i];
        }
    }

    float inv_tau = __expf(-log_tau[0]);
    #pragma unroll
    for (int i = 0; i < 4; ++i) {
        float z = acc[i] * inv_tau;
        float m = z;
        #pragma unroll
        for (int o = 32; o > 0; o >>= 1) m = fmaxf(m, __shfl_xor(m, o));
        float e = __expf(z - m);
        float s = e;
        #pragma unroll
        for (int o = 32; o > 0; o >>= 1) s += __shfl_xor(s, o);
        long oi = (row0 + g * 4 + i) * KOUT + c;
        outS[oi] = e / s;
        outL[oi] = acc[i];
    }
}

extern "C" void kernel_launch(void* const* d_in, const int* in_sizes, int n_in,
                              void* d_out, int out_size, void* d_ws, size_t ws_size,
                              hipStream_t stream)
{
    const float* x      = (const float*)d_in[0];
    const int*   ei     = (const int*)d_in[1];
    const float* W1a    = (const float*)d_in[2];
    const float* b1a    = (const float*)d_in[3];
    const float* W1b    = (const float*)d_in[4];
    const float* b1b    = (const float*)d_in[5];
    const float* eps1   = (const float*)d_in[6];
    const float* gamma1 = (const float*)d_in[7];
    const float* beta1  = (const float*)d_in[8];
    const float* W2a    = (const float*)d_in[9];
    const float* b2a    = (const float*)d_in[10];
    const float* W2b    = (const float*)d_in[11];
    const float* b2b    = (const float*)d_in[12];
    const float* eps2   = (const float*)d_in[13];
    const float* gamma2 = (const float*)d_in[14];
    const float* beta2  = (const float*)d_in[15];
    const float* Wout   = (const float*)d_in[16];
    const float* ltau   = (const float*)d_in[17];

    const size_t NB = (size_t)NNODES * HD;
    float* B0 = (float*)d_ws;
    float* B1 = B0 + NB;
    float* B2 = B1 + NB;
    float* ST = B2 + NB;             // stats: 4 x [8][128] classed + scales
    float* sum1 = ST, *sq1 = ST + 1024, *sum2 = ST + 2048, *sq2 = ST + 3072;
    float* scale1 = ST + 4096, *shift1 = ST + 4224;
    float* scale2 = ST + 4352, *shift2 = ST + 4480;

    unsigned short* xh  = (unsigned short*)B2;   // f16 x (CSR + gather1)
    unsigned short* h0h = (unsigned short*)B0;   // gather1 out; mlp1 in-place -> hh
    unsigned short* hh  = (unsigned short*)B0;   // h1 f16
    unsigned short* h2h = (unsigned short*)B2;   // gather2 out

    int* I0        = (int*)(ST + 4608);
    int* deg       = I0;
    int* incl      = I0 + NODE_PAD;
    int* row_start = I0 + 2 * NODE_PAD;
    int* row_end   = I0 + 3 * NODE_PAD;
    int* bsum      = I0 + 4 * NODE_PAD;
    int* col       = bsum + 256;                // NEDGES ints
    int* cnt       = col + NEDGES;              // [64][NODE_PAD] ints = 12.8MB
    unsigned short* wt1a = (unsigned short*)(cnt + NCHUNK * NODE_PAD);
    unsigned short* wt1b = wt1a + HD * HD;
    unsigned short* wt2a = wt1b + HD * HD;
    unsigned short* wt2b = wt2a + HD * HD;

    const int SCAN_BLKS = (NNODES + 255) / 256;   // 196
    const int GEMM_BLKS = (NNODES + 127) / 128;   // 391 (M=128 tile)
    const int GATH_BLKS = (NNODES + 31) / 32;     // 1563 (32 nodes/block)

    hipMemsetAsync(ST, 0, 4096 * sizeof(float), stream);
    prep_all<<<HIST_BLKS + 6506, 256, 0, stream>>>(x, xh, W1a, W1b, W2a, W2b,
                                                   wt1a, wt1b, wt2a, wt2b, ei, cnt);
    scan_a<<<SCAN_BLKS, 256, 0, stream>>>(cnt, deg, incl, bsum);
    scan_c<<<SCAN_BLKS, 256, 0, stream>>>(deg, incl, bsum, row_start, row_end);
    edge_fill<<<HIST_BLKS, 256, 0, stream>>>(ei, row_start, cnt, col);

    // ---- layer 1
    gin_gather_w<false><<<GATH_BLKS, 256, 0, stream>>>(
        xh, col, row_start, row_end, eps1, nullptr, nullptr, h0h);
    mlp_mfma<<<GEMM_BLKS, 512, 0, stream>>>(
        h0h, wt1a, b1a, wt1b, b1b, hh, nullptr, sum1, sq1);
    bn_prep<<<1, 128, 0, stream>>>(sum1, sq1, gamma1, beta1, scale1, shift1);

    // ---- layer 2 (BN1+ReLU fused into gather reads)
    gin_gather_w<true><<<GATH_BLKS, 256, 0, stream>>>(
        hh, col, row_start, row_end, eps2, scale1, shift1, h2h);
    mlp_mfma<<<GEMM_BLKS, 512, 0, stream>>>(
        h2h, wt2a, b2a, wt2b, b2b, nullptr, B1, sum2, sq2);
    bn_prep<<<1, 128, 0, stream>>>(sum2, sq2, gamma2, beta2, scale2, shift2);

    // ---- projection + softmax (BN2+ReLU fused on load)
    out_proj_softmax<<<NNODES / 16, 256, 0, stream>>>(
        B1, Wout, scale2, shift2, ltau,
        (float*)d_out, (float*)d_out + (size_t)NNODES * KOUT);
}